// Round 1
// baseline (678.323 us; speedup 1.0000x reference)
//
#include <hip/hip_runtime.h>
#include <hip/hip_bf16.h>
#include <math.h>

typedef __hip_bfloat16 bf16;
typedef __attribute__((ext_vector_type(8))) short short8;   // 8 x bf16 bits (4 VGPRs)
typedef __attribute__((ext_vector_type(4))) float f32x4;

static constexpr int BB   = 2;
static constexpr int SS   = 2048;
static constexpr int DD   = 2048;
static constexpr int NH   = 16;
static constexpr int HDD  = 128;
static constexpr int LATD = 512;
static constexpr int MR   = BB * SS;   // 4096 token rows

__device__ __forceinline__ void async_cp16(const void* g, void* l) {
    __builtin_amdgcn_global_load_lds(
        (const __attribute__((address_space(1))) void*)g,
        (__attribute__((address_space(3))) void*)l, 16, 0, 0);
}

__device__ __forceinline__ unsigned short bf_bits(bf16 v) {
    union { bf16 b; unsigned short u; } cv; cv.b = v; return cv.u;
}

// ---------------- cast f32 -> bf16, vectorized x4 ----------------
__global__ void cast_f32_bf16(const float4* __restrict__ in,
                              ushort4* __restrict__ out, int n4) {
    int i = blockIdx.x * blockDim.x + threadIdx.x;
    if (i >= n4) return;
    float4 v = in[i];
    ushort4 o;
    o.x = bf_bits(__float2bfloat16(v.x));
    o.y = bf_bits(__float2bfloat16(v.y));
    o.z = bf_bits(__float2bfloat16(v.z));
    o.w = bf_bits(__float2bfloat16(v.w));
    out[i] = o;
}

// ---------- transpose + cast: in[rows][cols] f32 -> out[cols][rows] bf16 ----------
__global__ void transpose_cast(const float* __restrict__ in,
                               bf16* __restrict__ out, int rows, int cols) {
    __shared__ float tile[32][33];              // +1 pad: no bank conflicts
    int tx = threadIdx.x & 31, ty = threadIdx.x >> 5;   // 32 x 8 threads
    int c0 = blockIdx.x * 32, r0 = blockIdx.y * 32;
    for (int i = 0; i < 32; i += 8)
        tile[ty + i][tx] = in[(size_t)(r0 + ty + i) * cols + c0 + tx];
    __syncthreads();
    for (int i = 0; i < 32; i += 8)
        out[(size_t)(c0 + ty + i) * rows + r0 + tx] =
            __float2bfloat16(tile[tx][ty + i]);
}

// ---------------- m97-style GEMM: C[M][N] = A[M][K] * Bt[N][K]^T ----------------
// 128x128 tile, BK=32, 256 threads (2x2 waves, 4x4 16x16 accs each).
template <bool OUT_F32>
__global__ __launch_bounds__(256) void gemm_bt(
    const bf16* __restrict__ A, const bf16* __restrict__ Bt,
    void* __restrict__ Cout, int M, int N, int K) {
    __shared__ bf16 As[128 * 32];
    __shared__ bf16 Bs[128 * 32];
    const int tid  = threadIdx.x;
    const int lane = tid & 63, wave = tid >> 6;
    const int quad = lane >> 4, l16 = lane & 15;
    const int row0 = blockIdx.y * 128, col0 = blockIdx.x * 128;
    const int wm = (wave >> 1) * 64, wn = (wave & 1) * 64;
    const int srow = lane >> 2;          // row within 16-row chunk
    const int scol = (lane & 3) * 8;     // k-offset (elements)

    f32x4 acc[4][4];
    for (int i = 0; i < 4; ++i)
        for (int j = 0; j < 4; ++j)
            for (int r = 0; r < 4; ++r) acc[i][j][r] = 0.f;

    for (int k0 = 0; k0 < K; k0 += 32) {
        __syncthreads();                 // protect LDS reuse
        for (int c = 0; c < 2; ++c) {
            const int chunk = wave * 2 + c;          // 8 chunks of 1KB each
            const int r = chunk * 16 + srow;
            async_cp16(A  + (size_t)(row0 + r) * K + k0 + scol, &As[chunk * 512]);
            async_cp16(Bt + (size_t)(col0 + r) * K + k0 + scol, &Bs[chunk * 512]);
        }
        __builtin_amdgcn_s_waitcnt(0);   // drain global_load_lds
        __syncthreads();

        short8 af[4], bfr[4];
        for (int t = 0; t < 4; ++t) {
            af[t]  = *(const short8*)&As[(wm + t * 16 + l16) * 32 + quad * 8];
            bfr[t] = *(const short8*)&Bs[(wn + t * 16 + l16) * 32 + quad * 8];
        }
        for (int i = 0; i < 4; ++i)
            for (int j = 0; j < 4; ++j)
                acc[i][j] = __builtin_amdgcn_mfma_f32_16x16x32_bf16(
                    af[i], bfr[j], acc[i][j], 0, 0, 0);
    }

    // C/D layout: row=(lane>>4)*4+reg, col=lane&15  [m89/m91 verified]
    const int rbase = row0 + wm + quad * 4;
    const int cbase = col0 + wn + l16;
    if (OUT_F32) {
        float* C = (float*)Cout;
        for (int i = 0; i < 4; ++i)
            for (int j = 0; j < 4; ++j)
                for (int r = 0; r < 4; ++r)
                    C[(size_t)(rbase + i * 16 + r) * N + cbase + j * 16] = acc[i][j][r];
    } else {
        bf16* C = (bf16*)Cout;
        for (int i = 0; i < 4; ++i)
            for (int j = 0; j < 4; ++j)
                for (int r = 0; r < 4; ++r)
                    C[(size_t)(rbase + i * 16 + r) * N + cbase + j * 16] =
                        __float2bfloat16(acc[i][j][r]);
    }
}

// ---------------- RoPE on Q and K in place (pairs (2i, 2i+1)) ----------------
__global__ void rope_qk(bf16* __restrict__ Q, bf16* __restrict__ Kt,
                        const float* __restrict__ freqs, int n) {
    int idx = blockIdx.x * blockDim.x + threadIdx.x;
    if (idx >= n) return;
    const int i = idx & 63;                    // pair index within head
    const int s = (idx >> 10) & (SS - 1);      // sequence position
    const float f = freqs[s * 64 + i];
    float sn, c;
    __sincosf(f, &sn, &c);
    const size_t base = (size_t)(idx >> 6) * HDD + 2 * i;
    {
        float t0 = __bfloat162float(Q[base]), t1 = __bfloat162float(Q[base + 1]);
        Q[base]     = __float2bfloat16(t0 * c - t1 * sn);
        Q[base + 1] = __float2bfloat16(t0 * sn + t1 * c);
    }
    {
        float t0 = __bfloat162float(Kt[base]), t1 = __bfloat162float(Kt[base + 1]);
        Kt[base]     = __float2bfloat16(t0 * c - t1 * sn);
        Kt[base + 1] = __float2bfloat16(t0 * sn + t1 * c);
    }
}

// ---------------- causal flash attention ----------------
// grid (S/64, NH, BB); 256 threads = 4 waves; wave w handles q rows [w*16, w*16+16).
__global__ __launch_bounds__(256) void flash_attn(
    const bf16* __restrict__ Q, const bf16* __restrict__ Kg,
    const bf16* __restrict__ Vg, bf16* __restrict__ O) {
    const int qt = blockIdx.x, h = blockIdx.y, b = blockIdx.z;
    const int q0 = qt * 64;
    const int tid = threadIdx.x, lane = tid & 63, wave = tid >> 6;
    const int quad = lane >> 4, l16 = lane & 15;

    __shared__ bf16 Ks[64 * 128];     // [k][d]
    __shared__ bf16 Vt[128 * 64];     // [d][k] (transposed for PV B-frags)
    __shared__ bf16 Ps[4][16 * 64];   // per-wave P round-trip

    const size_t headoff = ((size_t)b * SS * NH + h) * HDD;
    const bf16* Qb = Q + headoff;
    const bf16* Kb = Kg + headoff;
    const bf16* Vb = Vg + headoff;
    const int rs = NH * HDD;          // 2048: row stride between seq positions

    // Q A-frags: A[m=l16][k=quad*8+j], 4 k-steps of 32 over HD=128
    short8 qf[4];
    {
        const bf16* qrow = Qb + (size_t)(q0 + wave * 16 + l16) * rs;
        for (int kk = 0; kk < 4; ++kk)
            qf[kk] = *(const short8*)(qrow + kk * 32 + quad * 8);
    }

    f32x4 accO[8];
    for (int i = 0; i < 8; ++i)
        for (int r = 0; r < 4; ++r) accO[i][r] = 0.f;
    float m_r[4], l_r[4];
    for (int r = 0; r < 4; ++r) { m_r[r] = -1e30f; l_r[r] = 0.f; }

    const float scale = 0.08838834764831845f;   // 1/sqrt(128)

    for (int kt = 0; kt <= qt; ++kt) {
        const int k0 = kt * 64;
        __syncthreads();   // previous iteration's LDS reads done
        // stage K tile [64][128] via global_load_lds (16 x 1KB chunks)
        for (int c = 0; c < 4; ++c) {
            const int chunk = wave * 4 + c;
            const int kr = chunk * 4 + (lane >> 4);
            async_cp16(Kb + (size_t)(k0 + kr) * rs + l16 * 8, &Ks[chunk * 512]);
        }
        // stage V^T manually: Vt[d][k] = V[k0+k][d]
        {
            const int kv = tid >> 2, dg = (tid & 3) * 32;
            const bf16* vrow = Vb + (size_t)(k0 + kv) * rs + dg;
            for (int u = 0; u < 4; ++u) {
                short8 v = *(const short8*)(vrow + u * 8);
                const bf16* ve = (const bf16*)&v;
                for (int e = 0; e < 8; ++e)
                    Vt[(dg + u * 8 + e) * 64 + kv] = ve[e];
            }
        }
        __builtin_amdgcn_s_waitcnt(0);
        __syncthreads();

        // S = Q K^T : [16 q][64 k] per wave
        f32x4 sfr[4];
        for (int nt = 0; nt < 4; ++nt)
            for (int r = 0; r < 4; ++r) sfr[nt][r] = 0.f;
        for (int kk = 0; kk < 4; ++kk)
            for (int nt = 0; nt < 4; ++nt) {
                short8 kf = *(const short8*)&Ks[(nt * 16 + l16) * 128 + kk * 32 + quad * 8];
                sfr[nt] = __builtin_amdgcn_mfma_f32_16x16x32_bf16(qf[kk], kf, sfr[nt], 0, 0, 0);
            }

        // scale + causal mask (only diagonal tile has masked entries)
        float sv[4][4];
        const int qg = q0 + wave * 16 + quad * 4;   // + r
        const bool diag = (kt == qt);
        for (int nt = 0; nt < 4; ++nt) {
            const int kgl = k0 + nt * 16 + l16;
            for (int r = 0; r < 4; ++r) {
                float s = sfr[nt][r] * scale;
                if (diag && kgl > qg + r) s = -1e30f;
                sv[nt][r] = s;
            }
        }
        // online softmax; row r of quad lives in lanes quad*16..quad*16+15
        float rmax[4];
        for (int r = 0; r < 4; ++r)
            rmax[r] = fmaxf(fmaxf(sv[0][r], sv[1][r]), fmaxf(sv[2][r], sv[3][r]));
        for (int off = 1; off < 16; off <<= 1)
            for (int r = 0; r < 4; ++r)
                rmax[r] = fmaxf(rmax[r], __shfl_xor(rmax[r], off));
        float alpha[4];
        for (int r = 0; r < 4; ++r) {
            const float mnew = fmaxf(m_r[r], rmax[r]);
            alpha[r] = __expf(m_r[r] - mnew);
            m_r[r] = mnew;
        }
        float pm[4][4], psum[4];
        for (int r = 0; r < 4; ++r) psum[r] = 0.f;
        for (int nt = 0; nt < 4; ++nt)
            for (int r = 0; r < 4; ++r) {
                const float p = __expf(sv[nt][r] - m_r[r]);   // masked -> exact 0
                pm[nt][r] = p;
                psum[r] += p;
            }
        for (int off = 1; off < 16; off <<= 1)
            for (int r = 0; r < 4; ++r)
                psum[r] += __shfl_xor(psum[r], off);
        for (int r = 0; r < 4; ++r) l_r[r] = l_r[r] * alpha[r] + psum[r];
        for (int nt = 0; nt < 8; ++nt)
            for (int r = 0; r < 4; ++r) accO[nt][r] *= alpha[r];

        // P -> LDS (C-layout write), re-read in A-layout
        for (int nt = 0; nt < 4; ++nt)
            for (int r = 0; r < 4; ++r)
                Ps[wave][(quad * 4 + r) * 64 + nt * 16 + l16] = __float2bfloat16(pm[nt][r]);
        __builtin_amdgcn_s_waitcnt(0xc07f);   // lgkmcnt(0): own-wave Ps writes visible

        // O += P V
        for (int ks = 0; ks < 2; ++ks) {
            short8 pf = *(const short8*)&Ps[wave][l16 * 64 + ks * 32 + quad * 8];
            for (int nt = 0; nt < 8; ++nt) {
                short8 vf = *(const short8*)&Vt[(nt * 16 + l16) * 64 + ks * 32 + quad * 8];
                accO[nt] = __builtin_amdgcn_mfma_f32_16x16x32_bf16(pf, vf, accO[nt], 0, 0, 0);
            }
        }
    }

    bf16* Ob = O + headoff;
    float inv[4];
    for (int r = 0; r < 4; ++r) inv[r] = 1.f / l_r[r];
    for (int nt = 0; nt < 8; ++nt)
        for (int r = 0; r < 4; ++r)
            Ob[(size_t)(q0 + wave * 16 + quad * 4 + r) * rs + nt * 16 + l16] =
                __float2bfloat16(accO[nt][r] * inv[r]);
}

extern "C" void kernel_launch(void* const* d_in, const int* in_sizes, int n_in,
                              void* d_out, int out_size, void* d_ws, size_t ws_size,
                              hipStream_t stream) {
    (void)in_sizes; (void)n_in; (void)out_size; (void)ws_size;
    const float* x     = (const float*)d_in[0];
    const float* freqs = (const float*)d_in[1];
    // d_in[2] = mask: exactly causal 0/-1e9 -> applied analytically in flash_attn
    const float* Wq    = (const float*)d_in[3];
    const float* Wdown = (const float*)d_in[4];
    const float* Wkup  = (const float*)d_in[5];
    const float* Wvup  = (const float*)d_in[6];
    const float* Wo    = (const float*)d_in[7];
    float* out = (float*)d_out;

    char* ws = (char*)d_ws;
    size_t off = 0;
    auto take = [&](size_t bytes) -> void* {
        void* p = ws + off;
        off += (bytes + 255) & ~(size_t)255;
        return p;
    };
    bf16* xb     = (bf16*)take((size_t)MR * DD * 2);     // 16 MB
    bf16* WqT    = (bf16*)take((size_t)DD * DD * 2);     //  8 MB
    bf16* WoT    = (bf16*)take((size_t)DD * DD * 2);     //  8 MB
    bf16* WdownT = (bf16*)take((size_t)LATD * DD * 2);   //  2 MB
    bf16* WkupT  = (bf16*)take((size_t)DD * LATD * 2);   //  2 MB
    bf16* WvupT  = (bf16*)take((size_t)DD * LATD * 2);   //  2 MB
    bf16* Qb     = (bf16*)take((size_t)MR * DD * 2);     // 16 MB
    bf16* Kb     = (bf16*)take((size_t)MR * DD * 2);     // 16 MB
    bf16* Vb     = (bf16*)take((size_t)MR * DD * 2);     // 16 MB
    bf16* ckv    = (bf16*)take((size_t)MR * LATD * 2);   //  4 MB
    bf16* attn   = (bf16*)take((size_t)MR * DD * 2);     // 16 MB  (total ~106 MB)

    cast_f32_bf16<<<(MR * DD / 4) / 256, 256, 0, stream>>>(
        (const float4*)x, (ushort4*)xb, MR * DD / 4);

    transpose_cast<<<dim3(DD / 32, DD / 32), 256, 0, stream>>>(Wq, WqT, DD, DD);
    transpose_cast<<<dim3(DD / 32, DD / 32), 256, 0, stream>>>(Wo, WoT, DD, DD);
    transpose_cast<<<dim3(LATD / 32, DD / 32), 256, 0, stream>>>(Wdown, WdownT, DD, LATD);
    transpose_cast<<<dim3(DD / 32, LATD / 32), 256, 0, stream>>>(Wkup, WkupT, LATD, DD);
    transpose_cast<<<dim3(DD / 32, LATD / 32), 256, 0, stream>>>(Wvup, WvupT, LATD, DD);

    // Q = x Wq ; c_kv = x Wdown ; K = c_kv Wkup ; V = c_kv Wvup
    gemm_bt<false><<<dim3(DD / 128, MR / 128), 256, 0, stream>>>(xb, WqT, Qb, MR, DD, DD);
    gemm_bt<false><<<dim3(LATD / 128, MR / 128), 256, 0, stream>>>(xb, WdownT, ckv, MR, LATD, DD);
    gemm_bt<false><<<dim3(DD / 128, MR / 128), 256, 0, stream>>>(ckv, WkupT, Kb, MR, DD, LATD);
    gemm_bt<false><<<dim3(DD / 128, MR / 128), 256, 0, stream>>>(ckv, WvupT, Vb, MR, DD, LATD);

    rope_qk<<<(BB * SS * NH * 64) / 256, 256, 0, stream>>>(Qb, Kb, freqs, BB * SS * NH * 64);

    flash_attn<<<dim3(SS / 64, NH, BB), 256, 0, stream>>>(Qb, Kb, Vb, attn);

    // out = attn Wo (fp32 epilogue straight to d_out)
    gemm_bt<true><<<dim3(DD / 128, MR / 128), 256, 0, stream>>>(attn, WoT, out, MR, DD, DD);
}

// Round 2
// 557.732 us; speedup vs baseline: 1.2162x; 1.2162x over previous
//
#include <hip/hip_runtime.h>
#include <hip/hip_bf16.h>
#include <math.h>

typedef __hip_bfloat16 bf16;
typedef __attribute__((ext_vector_type(8))) short short8;   // 8 x bf16 bits (4 VGPRs)
typedef __attribute__((ext_vector_type(4))) float f32x4;

static constexpr int BB   = 2;
static constexpr int SS   = 2048;
static constexpr int DD   = 2048;
static constexpr int NH   = 16;
static constexpr int HDD  = 128;
static constexpr int LATD = 512;
static constexpr int MR   = BB * SS;   // 4096 token rows

__device__ __forceinline__ void async_cp16(const void* g, void* l) {
    __builtin_amdgcn_global_load_lds(
        (const __attribute__((address_space(1))) void*)g,
        (__attribute__((address_space(3))) void*)l, 16, 0, 0);
}

__device__ __forceinline__ unsigned short bf_bits(bf16 v) {
    union { bf16 b; unsigned short u; } cv; cv.b = v; return cv.u;
}

// ---------------- cast f32 -> bf16, vectorized x4 ----------------
__global__ void cast_f32_bf16(const float4* __restrict__ in,
                              ushort4* __restrict__ out, int n4) {
    int i = blockIdx.x * blockDim.x + threadIdx.x;
    if (i >= n4) return;
    float4 v = in[i];
    ushort4 o;
    o.x = bf_bits(__float2bfloat16(v.x));
    o.y = bf_bits(__float2bfloat16(v.y));
    o.z = bf_bits(__float2bfloat16(v.z));
    o.w = bf_bits(__float2bfloat16(v.w));
    out[i] = o;
}

// ---------- transpose + cast: in[rows][cols] f32 -> out[cols][rows] bf16 ----------
__global__ void transpose_cast(const float* __restrict__ in,
                               bf16* __restrict__ out, int rows, int cols) {
    __shared__ float tile[32][33];              // +1 pad: no bank conflicts
    int tx = threadIdx.x & 31, ty = threadIdx.x >> 5;   // 32 x 8 threads
    int c0 = blockIdx.x * 32, r0 = blockIdx.y * 32;
    for (int i = 0; i < 32; i += 8)
        tile[ty + i][tx] = in[(size_t)(r0 + ty + i) * cols + c0 + tx];
    __syncthreads();
    for (int i = 0; i < 32; i += 8)
        out[(size_t)(c0 + ty + i) * rows + r0 + tx] =
            __float2bfloat16(tile[tx][ty + i]);
}

// ---------------- m97-style GEMM: C[M][N] = A[M][K] * Bt[N][K]^T ----------------
template <bool OUT_F32>
__global__ __launch_bounds__(256) void gemm_bt(
    const bf16* __restrict__ A, const bf16* __restrict__ Bt,
    void* __restrict__ Cout, int M, int N, int K) {
    __shared__ bf16 As[128 * 32];
    __shared__ bf16 Bs[128 * 32];
    const int tid  = threadIdx.x;
    const int lane = tid & 63, wave = tid >> 6;
    const int quad = lane >> 4, l16 = lane & 15;
    const int row0 = blockIdx.y * 128, col0 = blockIdx.x * 128;
    const int wm = (wave >> 1) * 64, wn = (wave & 1) * 64;
    const int srow = lane >> 2;
    const int scol = (lane & 3) * 8;

    f32x4 acc[4][4];
    for (int i = 0; i < 4; ++i)
        for (int j = 0; j < 4; ++j)
            for (int r = 0; r < 4; ++r) acc[i][j][r] = 0.f;

    for (int k0 = 0; k0 < K; k0 += 32) {
        __syncthreads();
        for (int c = 0; c < 2; ++c) {
            const int chunk = wave * 2 + c;
            const int r = chunk * 16 + srow;
            async_cp16(A  + (size_t)(row0 + r) * K + k0 + scol, &As[chunk * 512]);
            async_cp16(Bt + (size_t)(col0 + r) * K + k0 + scol, &Bs[chunk * 512]);
        }
        __builtin_amdgcn_s_waitcnt(0);
        __syncthreads();

        short8 af[4], bfr[4];
        for (int t = 0; t < 4; ++t) {
            af[t]  = *(const short8*)&As[(wm + t * 16 + l16) * 32 + quad * 8];
            bfr[t] = *(const short8*)&Bs[(wn + t * 16 + l16) * 32 + quad * 8];
        }
        for (int i = 0; i < 4; ++i)
            for (int j = 0; j < 4; ++j)
                acc[i][j] = __builtin_amdgcn_mfma_f32_16x16x32_bf16(
                    af[i], bfr[j], acc[i][j], 0, 0, 0);
    }

    const int rbase = row0 + wm + quad * 4;
    const int cbase = col0 + wn + l16;
    if (OUT_F32) {
        float* C = (float*)Cout;
        for (int i = 0; i < 4; ++i)
            for (int j = 0; j < 4; ++j)
                for (int r = 0; r < 4; ++r)
                    C[(size_t)(rbase + i * 16 + r) * N + cbase + j * 16] = acc[i][j][r];
    } else {
        bf16* C = (bf16*)Cout;
        for (int i = 0; i < 4; ++i)
            for (int j = 0; j < 4; ++j)
                for (int r = 0; r < 4; ++r)
                    C[(size_t)(rbase + i * 16 + r) * N + cbase + j * 16] =
                        __float2bfloat16(acc[i][j][r]);
    }
}

// ---------------- RoPE on Q (stride 2048) and K-in-KV (stride 4096), vectorized ----------------
__global__ void rope_qk(bf16* __restrict__ Q, bf16* __restrict__ KV,
                        const float* __restrict__ freqs, int n) {
    int idx = blockIdx.x * blockDim.x + threadIdx.x;
    if (idx >= n) return;
    const int pg  = idx & 15;            // 4-pair group: d = pg*8 .. pg*8+7
    const int h   = (idx >> 4) & (NH - 1);
    const int tok = idx >> 8;
    const int s   = tok & (SS - 1);
    const float4 f = *(const float4*)&freqs[s * 64 + pg * 4];
    float cs[4], sn[4];
    cs[0] = __cosf(f.x); sn[0] = __sinf(f.x);
    cs[1] = __cosf(f.y); sn[1] = __sinf(f.y);
    cs[2] = __cosf(f.z); sn[2] = __sinf(f.z);
    cs[3] = __cosf(f.w); sn[3] = __sinf(f.w);

    bf16* qp = Q  + (size_t)tok * DD   + h * HDD + pg * 8;
    bf16* kp = KV + (size_t)tok * 4096 + h * HDD + pg * 8;
    for (int pass = 0; pass < 2; ++pass) {
        bf16* p = pass ? kp : qp;
        short8 v = *(const short8*)p;
        const bf16* ve = (const bf16*)&v;
        short8 o;
        bf16* oe = (bf16*)&o;
        for (int i = 0; i < 4; ++i) {
            float t0 = __bfloat162float(ve[2 * i]);
            float t1 = __bfloat162float(ve[2 * i + 1]);
            oe[2 * i]     = __float2bfloat16(t0 * cs[i] - t1 * sn[i]);
            oe[2 * i + 1] = __float2bfloat16(t0 * sn[i] + t1 * cs[i]);
        }
        *(short8*)p = o;
    }
}

// ---------------- causal flash attention, BQ=128, BKV=64 ----------------
// grid (S/128 [reversed], NH, BB); 256 threads = 4 waves; wave w: q rows [w*32, w*32+32)
// as 2 m-tiles of 16. LDS block layouts for conflict-free b128 reads:
//   Ks[kk=4][r=64][32]  (K-tile, staged via global_load_lds per-lane src addressing)
//   Vt[ks=2][d=128][32] (V^T, register 8x4 micro-transpose, ds_write_b64 contiguous-kv)
//   Ps[wave][16][72]    (P round-trip, padded stride)
__global__ __launch_bounds__(256) void flash_attn(
    const bf16* __restrict__ Q, const bf16* __restrict__ KV,
    bf16* __restrict__ O) {
    const int nQT = SS / 128;
    const int qt = (nQT - 1) - blockIdx.x;        // longest blocks first
    const int h = blockIdx.y, b = blockIdx.z;
    const int q0 = qt * 128;
    const int tid = threadIdx.x, lane = tid & 63, wave = tid >> 6;
    const int quad = lane >> 4, l16 = lane & 15;

    __shared__ bf16 Ks[4 * 64 * 32];     // 16 KB
    __shared__ bf16 Vt[2 * 128 * 32];    // 16 KB
    __shared__ bf16 Ps[4][16 * 72];      // 9 KB

    const bf16* Qb = Q  + (size_t)b * SS * DD   + h * HDD;
    const bf16* Kb = KV + (size_t)b * SS * 4096 + h * HDD;
    const bf16* Vb = Kb + 2048;
    const int qrs = DD, krs = 4096;

    // Q A-frags: 2 m-tiles x 4 k-steps
    short8 qf[2][4];
    for (int mt = 0; mt < 2; ++mt) {
        const bf16* qrow = Qb + (size_t)(q0 + wave * 32 + mt * 16 + l16) * qrs;
        for (int kk = 0; kk < 4; ++kk)
            qf[mt][kk] = *(const short8*)(qrow + kk * 32 + quad * 8);
    }

    f32x4 accO[2][8];
    for (int mt = 0; mt < 2; ++mt)
        for (int i = 0; i < 8; ++i)
            for (int r = 0; r < 4; ++r) accO[mt][i][r] = 0.f;
    float m_r[2][4], l_r[2][4];
    for (int mt = 0; mt < 2; ++mt)
        for (int r = 0; r < 4; ++r) { m_r[mt][r] = -1e30f; l_r[mt][r] = 0.f; }

    const float scale = 0.08838834764831845f;   // 1/sqrt(128)
    const int ktMax = 2 * qt + 1;

    for (int kt = 0; kt <= ktMax; ++kt) {
        const int k0 = kt * 64;
        __syncthreads();                          // previous iter's LDS reads done

        // ---- stage K tile into Ks[kk][r][32]; wave w covers kk=w ----
        {
            const int kk = wave;
            for (int i = 0; i < 4; ++i) {
                const int r0 = i * 16;
                const int r = r0 + (lane >> 2), j = (lane & 3) * 8;
                async_cp16(Kb + (size_t)(k0 + r) * krs + kk * 32 + j,
                           &Ks[kk * 2048 + r0 * 32]);
            }
        }
        // ---- stage V^T into Vt[ks][d][32] via 8x4 register micro-transpose ----
        {
            const int dg = (tid & 15) * 8, kv4 = (tid >> 4) * 4;
            const bf16* vb0 = Vb + (size_t)(k0 + kv4) * krs + dg;
            short8 row[4];
            for (int r = 0; r < 4; ++r)
                row[r] = *(const short8*)(vb0 + (size_t)r * krs);
            const int ks = kv4 >> 5, inner = kv4 & 31;
            const bf16* re0 = (const bf16*)&row[0];
            const bf16* re1 = (const bf16*)&row[1];
            const bf16* re2 = (const bf16*)&row[2];
            const bf16* re3 = (const bf16*)&row[3];
            for (int j = 0; j < 8; ++j) {
                ushort4 w;
                w.x = bf_bits(re0[j]); w.y = bf_bits(re1[j]);
                w.z = bf_bits(re2[j]); w.w = bf_bits(re3[j]);
                *(ushort4*)&Vt[ks * 4096 + (dg + j) * 32 + inner] = w;
            }
        }
        __builtin_amdgcn_s_waitcnt(0);
        __syncthreads();

        const bool diag = (kt >= 2 * qt);
        for (int mt = 0; mt < 2; ++mt) {
            // ---- S = Q K^T : [16 q][64 k] ----
            f32x4 sfr[4];
            for (int nt = 0; nt < 4; ++nt)
                for (int r = 0; r < 4; ++r) sfr[nt][r] = 0.f;
            for (int kk = 0; kk < 4; ++kk)
                for (int nt = 0; nt < 4; ++nt) {
                    short8 kf = *(const short8*)
                        &Ks[kk * 2048 + (nt * 16 + l16) * 32 + quad * 8];
                    sfr[nt] = __builtin_amdgcn_mfma_f32_16x16x32_bf16(
                        qf[mt][kk], kf, sfr[nt], 0, 0, 0);
                }

            // ---- scale + causal mask ----
            float sv[4][4];
            const int qg = q0 + wave * 32 + mt * 16 + quad * 4;
            for (int nt = 0; nt < 4; ++nt) {
                const int kgl = k0 + nt * 16 + l16;
                for (int r = 0; r < 4; ++r) {
                    float s = sfr[nt][r] * scale;
                    if (diag && kgl > qg + r) s = -1e30f;
                    sv[nt][r] = s;
                }
            }
            // ---- online softmax (row r in quad; cols across l16) ----
            float rmax[4];
            for (int r = 0; r < 4; ++r)
                rmax[r] = fmaxf(fmaxf(sv[0][r], sv[1][r]), fmaxf(sv[2][r], sv[3][r]));
            for (int off = 1; off < 16; off <<= 1)
                for (int r = 0; r < 4; ++r)
                    rmax[r] = fmaxf(rmax[r], __shfl_xor(rmax[r], off));
            float alpha[4];
            for (int r = 0; r < 4; ++r) {
                const float mnew = fmaxf(m_r[mt][r], rmax[r]);
                alpha[r] = __expf(m_r[mt][r] - mnew);
                m_r[mt][r] = mnew;
            }
            float pm[4][4], psum[4];
            for (int r = 0; r < 4; ++r) psum[r] = 0.f;
            for (int nt = 0; nt < 4; ++nt)
                for (int r = 0; r < 4; ++r) {
                    const float p = __expf(sv[nt][r] - m_r[mt][r]);
                    pm[nt][r] = p;
                    psum[r] += p;
                }
            for (int off = 1; off < 16; off <<= 1)
                for (int r = 0; r < 4; ++r)
                    psum[r] += __shfl_xor(psum[r], off);
            for (int r = 0; r < 4; ++r)
                l_r[mt][r] = l_r[mt][r] * alpha[r] + psum[r];
            for (int nt = 0; nt < 8; ++nt)
                for (int r = 0; r < 4; ++r) accO[mt][nt][r] *= alpha[r];

            // ---- P -> LDS (C-layout write, padded stride 72), re-read A-layout ----
            for (int nt = 0; nt < 4; ++nt)
                for (int r = 0; r < 4; ++r)
                    Ps[wave][(quad * 4 + r) * 72 + nt * 16 + l16] =
                        __float2bfloat16(pm[nt][r]);
            __builtin_amdgcn_s_waitcnt(0xc07f);   // lgkmcnt(0)

            // ---- O += P V ----
            for (int ks = 0; ks < 2; ++ks) {
                short8 pf = *(const short8*)
                    &Ps[wave][l16 * 72 + ks * 32 + quad * 8];
                for (int nt = 0; nt < 8; ++nt) {
                    short8 vf = *(const short8*)
                        &Vt[ks * 4096 + (nt * 16 + l16) * 32 + quad * 8];
                    accO[mt][nt] = __builtin_amdgcn_mfma_f32_16x16x32_bf16(
                        pf, vf, accO[mt][nt], 0, 0, 0);
                }
            }
            __builtin_amdgcn_s_waitcnt(0xc07f);   // pf reads done before next mt rewrite
        }
    }

    bf16* Ob = O + (size_t)b * SS * DD + h * HDD;
    for (int mt = 0; mt < 2; ++mt) {
        float inv[4];
        for (int r = 0; r < 4; ++r) inv[r] = 1.f / l_r[mt][r];
        for (int nt = 0; nt < 8; ++nt)
            for (int r = 0; r < 4; ++r)
                Ob[(size_t)(q0 + wave * 32 + mt * 16 + quad * 4 + r) * qrs +
                   nt * 16 + l16] = __float2bfloat16(accO[mt][nt][r] * inv[r]);
    }
}

extern "C" void kernel_launch(void* const* d_in, const int* in_sizes, int n_in,
                              void* d_out, int out_size, void* d_ws, size_t ws_size,
                              hipStream_t stream) {
    (void)in_sizes; (void)n_in; (void)out_size; (void)ws_size;
    const float* x     = (const float*)d_in[0];
    const float* freqs = (const float*)d_in[1];
    // d_in[2] = mask: exactly causal 0/-1e9 -> applied analytically in flash_attn
    const float* Wq    = (const float*)d_in[3];
    const float* Wdown = (const float*)d_in[4];
    const float* Wkup  = (const float*)d_in[5];
    const float* Wvup  = (const float*)d_in[6];
    const float* Wo    = (const float*)d_in[7];
    float* out = (float*)d_out;

    char* ws = (char*)d_ws;
    size_t off = 0;
    auto take = [&](size_t bytes) -> void* {
        void* p = ws + off;
        off += (bytes + 255) & ~(size_t)255;
        return p;
    };
    bf16* xb     = (bf16*)take((size_t)MR * DD * 2);       // 16 MB
    bf16* WqT    = (bf16*)take((size_t)DD * DD * 2);       //  8 MB
    bf16* WoT    = (bf16*)take((size_t)DD * DD * 2);       //  8 MB
    bf16* WdownT = (bf16*)take((size_t)LATD * DD * 2);     //  2 MB
    bf16* WkvT   = (bf16*)take((size_t)2 * DD * LATD * 2); //  4 MB (Kup rows then Vup rows)
    bf16* Qb     = (bf16*)take((size_t)MR * DD * 2);       // 16 MB
    bf16* KVb    = (bf16*)take((size_t)MR * 2 * DD * 2);   // 32 MB [tok][K 2048 | V 2048]
    bf16* ckv    = (bf16*)take((size_t)MR * LATD * 2);     //  4 MB
    bf16* attn   = (bf16*)take((size_t)MR * DD * 2);       // 16 MB   (total ~106 MB)

    cast_f32_bf16<<<(MR * DD / 4) / 256, 256, 0, stream>>>(
        (const float4*)x, (ushort4*)xb, MR * DD / 4);

    transpose_cast<<<dim3(DD / 32, DD / 32), 256, 0, stream>>>(Wq, WqT, DD, DD);
    transpose_cast<<<dim3(DD / 32, DD / 32), 256, 0, stream>>>(Wo, WoT, DD, DD);
    transpose_cast<<<dim3(LATD / 32, DD / 32), 256, 0, stream>>>(Wdown, WdownT, DD, LATD);
    transpose_cast<<<dim3(DD / 32, LATD / 32), 256, 0, stream>>>(Wkup, WkvT, LATD, DD);
    transpose_cast<<<dim3(DD / 32, LATD / 32), 256, 0, stream>>>(
        Wvup, WkvT + (size_t)DD * LATD, LATD, DD);

    // Q = x Wq ; c_kv = x Wdown ; [K|V] = c_kv [Wkup|Wvup]
    gemm_bt<false><<<dim3(DD / 128, MR / 128), 256, 0, stream>>>(xb, WqT, Qb, MR, DD, DD);
    gemm_bt<false><<<dim3(LATD / 128, MR / 128), 256, 0, stream>>>(xb, WdownT, ckv, MR, LATD, DD);
    gemm_bt<false><<<dim3(2 * DD / 128, MR / 128), 256, 0, stream>>>(ckv, WkvT, KVb, MR, 2 * DD, LATD);

    rope_qk<<<(MR * NH * 16) / 256, 256, 0, stream>>>(Qb, KVb, freqs, MR * NH * 16);

    flash_attn<<<dim3(SS / 128, NH, BB), 256, 0, stream>>>(Qb, KVb, attn);

    // out = attn Wo (fp32 epilogue straight to d_out)
    gemm_bt<true><<<dim3(DD / 128, MR / 128), 256, 0, stream>>>(attn, WoT, out, MR, DD, DD);
}

// Round 3
// 482.221 us; speedup vs baseline: 1.4067x; 1.1566x over previous
//
#include <hip/hip_runtime.h>
#include <hip/hip_bf16.h>
#include <math.h>

typedef __hip_bfloat16 bf16;
typedef __attribute__((ext_vector_type(8))) short short8;   // 8 x bf16 bits (4 VGPRs)
typedef __attribute__((ext_vector_type(4))) float f32x4;

static constexpr int BB   = 2;
static constexpr int SS   = 2048;
static constexpr int DD   = 2048;
static constexpr int NH   = 16;
static constexpr int HDD  = 128;
static constexpr int LATD = 512;
static constexpr int MR   = BB * SS;   // 4096 token rows
static constexpr int QRS  = DD + LATD; // 2560: row stride of merged [Q | c_kv] buffer

__device__ __forceinline__ void async_cp16(const void* g, void* l) {
    __builtin_amdgcn_global_load_lds(
        (const __attribute__((address_space(1))) void*)g,
        (__attribute__((address_space(3))) void*)l, 16, 0, 0);
}

__device__ __forceinline__ unsigned short bf_bits(bf16 v) {
    union { bf16 b; unsigned short u; } cv; cv.b = v; return cv.u;
}

// ---------------- cast f32 -> bf16, vectorized x4 ----------------
__global__ void cast_f32_bf16(const float4* __restrict__ in,
                              ushort4* __restrict__ out, int n4) {
    int i = blockIdx.x * blockDim.x + threadIdx.x;
    if (i >= n4) return;
    float4 v = in[i];
    ushort4 o;
    o.x = bf_bits(__float2bfloat16(v.x));
    o.y = bf_bits(__float2bfloat16(v.y));
    o.z = bf_bits(__float2bfloat16(v.z));
    o.w = bf_bits(__float2bfloat16(v.w));
    out[i] = o;
}

// ---------- transpose + cast: in[rows][cols] f32 -> out[cols][rows] bf16 ----------
__global__ void transpose_cast(const float* __restrict__ in,
                               bf16* __restrict__ out, int rows, int cols) {
    __shared__ float tile[32][33];
    int tx = threadIdx.x & 31, ty = threadIdx.x >> 5;   // 32 x 8 threads
    int c0 = blockIdx.x * 32, r0 = blockIdx.y * 32;
    for (int i = 0; i < 32; i += 8)
        tile[ty + i][tx] = in[(size_t)(r0 + ty + i) * cols + c0 + tx];
    __syncthreads();
    for (int i = 0; i < 32; i += 8)
        out[(size_t)(c0 + ty + i) * rows + r0 + tx] =
            __float2bfloat16(tile[tx][ty + i]);
}

// ---- V pre-transpose: VT[bh][d][s] (bf16) from KV's V half, kv-group XOR swizzle ----
// Within each 64-s tile, group g (8 s-values) stored at position g ^ (d & 7) so that
// flash PV B-frag reads hit 8 uniform start banks.
__global__ void transpose_v(const bf16* __restrict__ KV, bf16* __restrict__ VT) {
    __shared__ bf16 t[64][74];               // stride 74 elem: spreads column reads
    const int tid = threadIdx.x;
    const int s0 = blockIdx.x * 64, d0 = blockIdx.y * 64;
    const int bh = blockIdx.z, b = bh >> 4, h = bh & 15;
    const bf16* src = KV + (size_t)b * SS * 4096 + 2048 + h * 128 + d0;
    for (int p = 0; p < 2; ++p) {
        const int s = p * 32 + (tid >> 3), dc = (tid & 7) * 8;
        short8 v = *(const short8*)(src + (size_t)(s0 + s) * 4096 + dc);
        const bf16* ve = (const bf16*)&v;
        for (int e = 0; e < 8; ++e) t[s][dc + e] = ve[e];
    }
    __syncthreads();
    bf16* dst = VT + ((size_t)bh * HDD + d0) * SS + s0;
    for (int p = 0; p < 2; ++p) {
        const int d = p * 32 + (tid >> 3), g = tid & 7;
        short8 v; bf16* ve = (bf16*)&v;
        for (int e = 0; e < 8; ++e) ve[e] = t[g * 8 + e][d];
        const int gp = g ^ (d & 7);          // d0 is a multiple of 8: (d0+d)&7 == d&7
        *(short8*)(dst + (size_t)d * SS + gp * 8) = v;
    }
}

// ------- double-buffered GEMM: C[M][N] = A[M][K(lda)] * Bt[N][K(ldb)]^T -------
// 128x128 tile, BK=32, 256 threads. Single __syncthreads per K-step; next stage's
// DMAs are issued right after the sync and fly during compute (drained by the
// NEXT sync's auto vmcnt(0), which by then is nearly free).
template <bool OUT_F32>
__global__ __launch_bounds__(256) void gemm_bt(
    const bf16* __restrict__ A, const bf16* __restrict__ Bt,
    void* __restrict__ Cout, int M, int N, int K, int lda, int ldb, int ldc) {
    __shared__ bf16 As[2][128 * 32];
    __shared__ bf16 Bs[2][128 * 32];
    const int tid  = threadIdx.x;
    const int lane = tid & 63, wave = tid >> 6;
    const int quad = lane >> 4, l16 = lane & 15;
    const int row0 = blockIdx.y * 128, col0 = blockIdx.x * 128;
    const int wm = (wave >> 1) * 64, wn = (wave & 1) * 64;
    const int srow = lane >> 2;
    const int scol = (lane & 3) * 8;

    f32x4 acc[4][4];
    for (int i = 0; i < 4; ++i)
        for (int j = 0; j < 4; ++j)
            for (int r = 0; r < 4; ++r) acc[i][j][r] = 0.f;

    auto stage = [&](int k0, int bufi) {
        for (int c = 0; c < 2; ++c) {
            const int chunk = wave * 2 + c;
            const int r = chunk * 16 + srow;
            async_cp16(A  + (size_t)(row0 + r) * lda + k0 + scol, &As[bufi][chunk * 512]);
            async_cp16(Bt + (size_t)(col0 + r) * ldb + k0 + scol, &Bs[bufi][chunk * 512]);
        }
    };

    const int nk = K / 32;
    stage(0, 0);
    for (int ki = 0; ki < nk; ++ki) {
        __syncthreads();                    // drains stage ki; frees buf (ki+1)&1
        if (ki + 1 < nk) stage((ki + 1) * 32, (ki + 1) & 1);
        const int bi = ki & 1;
        short8 af[4], bfr[4];
        for (int t = 0; t < 4; ++t) {
            af[t]  = *(const short8*)&As[bi][(wm + t * 16 + l16) * 32 + quad * 8];
            bfr[t] = *(const short8*)&Bs[bi][(wn + t * 16 + l16) * 32 + quad * 8];
        }
        for (int i = 0; i < 4; ++i)
            for (int j = 0; j < 4; ++j)
                acc[i][j] = __builtin_amdgcn_mfma_f32_16x16x32_bf16(
                    af[i], bfr[j], acc[i][j], 0, 0, 0);
    }

    const int rbase = row0 + wm + quad * 4;
    const int cbase = col0 + wn + l16;
    if (OUT_F32) {
        float* C = (float*)Cout;
        for (int i = 0; i < 4; ++i)
            for (int j = 0; j < 4; ++j)
                for (int r = 0; r < 4; ++r)
                    C[(size_t)(rbase + i * 16 + r) * ldc + cbase + j * 16] = acc[i][j][r];
    } else {
        bf16* C = (bf16*)Cout;
        for (int i = 0; i < 4; ++i)
            for (int j = 0; j < 4; ++j)
                for (int r = 0; r < 4; ++r)
                    C[(size_t)(rbase + i * 16 + r) * ldc + cbase + j * 16] =
                        __float2bfloat16(acc[i][j][r]);
    }
}

// ------- RoPE on Q (in QC, stride 2560) and K (in KV, stride 4096), vectorized -------
__global__ void rope_qk(bf16* __restrict__ Q, bf16* __restrict__ KV,
                        const float* __restrict__ freqs, int n) {
    int idx = blockIdx.x * blockDim.x + threadIdx.x;
    if (idx >= n) return;
    const int pg  = idx & 15;
    const int h   = (idx >> 4) & (NH - 1);
    const int tok = idx >> 8;
    const int s   = tok & (SS - 1);
    const float4 f = *(const float4*)&freqs[s * 64 + pg * 4];
    float cs[4], sn[4];
    cs[0] = __cosf(f.x); sn[0] = __sinf(f.x);
    cs[1] = __cosf(f.y); sn[1] = __sinf(f.y);
    cs[2] = __cosf(f.z); sn[2] = __sinf(f.z);
    cs[3] = __cosf(f.w); sn[3] = __sinf(f.w);

    bf16* qp = Q  + (size_t)tok * QRS  + h * HDD + pg * 8;
    bf16* kp = KV + (size_t)tok * 4096 + h * HDD + pg * 8;
    for (int pass = 0; pass < 2; ++pass) {
        bf16* p = pass ? kp : qp;
        short8 v = *(const short8*)p;
        const bf16* ve = (const bf16*)&v;
        short8 o;
        bf16* oe = (bf16*)&o;
        for (int i = 0; i < 4; ++i) {
            float t0 = __bfloat162float(ve[2 * i]);
            float t1 = __bfloat162float(ve[2 * i + 1]);
            oe[2 * i]     = __float2bfloat16(t0 * cs[i] - t1 * sn[i]);
            oe[2 * i + 1] = __float2bfloat16(t0 * sn[i] + t1 * cs[i]);
        }
        *(short8*)p = o;
    }
}

// ------------- causal flash attention, BQ=128, BKV=64, double-buffered -------------
// grid (S/128 [reversed], NH, BB); 256 thr = 4 waves; wave w: q rows [w*32, w*32+32).
// K and (pre-transposed, swizzled) V staged by pure DMA into 2 LDS buffers.
__global__ __launch_bounds__(256) void flash_attn(
    const bf16* __restrict__ QC, const bf16* __restrict__ KV,
    const bf16* __restrict__ VTg, bf16* __restrict__ O) {
    const int nQT = SS / 128;
    const int qt = (nQT - 1) - blockIdx.x;        // longest blocks first
    const int h = blockIdx.y, b = blockIdx.z;
    const int bh = b * NH + h;
    const int q0 = qt * 128;
    const int tid = threadIdx.x, lane = tid & 63, wave = tid >> 6;
    const int quad = lane >> 4, l16 = lane & 15;

    __shared__ bf16 Ks[2][4 * 64 * 32];   // 2 x 16 KB, [kk][r][32]
    __shared__ bf16 Vt[2][128 * 64];      // 2 x 16 KB, [d][64] (kv-group swizzled)
    __shared__ bf16 Ps[4][16 * 72];       // 9 KB

    const bf16* Kb  = KV  + (size_t)b * SS * 4096 + h * HDD;
    const bf16* VTb = VTg + (size_t)bh * HDD * SS;
    const int krs = 4096;

    // Q A-frags: 2 m-tiles x 4 k-steps (from merged QC buffer, stride QRS)
    short8 qf[2][4];
    for (int mt = 0; mt < 2; ++mt) {
        const bf16* qrow = QC + (size_t)(b * SS + q0 + wave * 32 + mt * 16 + l16) * QRS
                              + h * HDD;
        for (int kk = 0; kk < 4; ++kk)
            qf[mt][kk] = *(const short8*)(qrow + kk * 32 + quad * 8);
    }

    auto stage = [&](int kt, int bufi) {
        const int k0 = kt * 64;
        // K tile: wave covers kk=wave, 4 chunks of 16 rows x 32 elem (1 KB)
        for (int i = 0; i < 4; ++i)
            async_cp16(Kb + (size_t)(k0 + i * 16 + (lane >> 2)) * krs
                           + wave * 32 + (lane & 3) * 8,
                       &Ks[bufi][wave * 2048 + i * 512]);
        // V^T tile: wave covers chunks wave*4..+3; chunk c = d rows c*8..c*8+7 (128 B each)
        for (int c2 = 0; c2 < 4; ++c2) {
            const int c = wave * 4 + c2;
            async_cp16(VTb + (size_t)(c * 8 + (lane >> 3)) * SS + k0 + (lane & 7) * 8,
                       &Vt[bufi][c * 512]);
        }
    };

    f32x4 accO[2][8];
    for (int mt = 0; mt < 2; ++mt)
        for (int i = 0; i < 8; ++i)
            for (int r = 0; r < 4; ++r) accO[mt][i][r] = 0.f;
    float m_r[2][4], l_r[2][4];
    for (int mt = 0; mt < 2; ++mt)
        for (int r = 0; r < 4; ++r) { m_r[mt][r] = -1e30f; l_r[mt][r] = 0.f; }

    const float scale = 0.08838834764831845f;   // 1/sqrt(128)
    const int ktMax = 2 * qt + 1;

    stage(0, 0);
    for (int kt = 0; kt <= ktMax; ++kt) {
        const int k0 = kt * 64;
        __syncthreads();                    // drains stage kt; frees buf (kt+1)&1
        if (kt < ktMax) stage(kt + 1, (kt + 1) & 1);
        const int bi = kt & 1;

        const bool diag = (kt >= 2 * qt);
        for (int mt = 0; mt < 2; ++mt) {
            // ---- S = Q K^T : [16 q][64 k] ----
            f32x4 sfr[4];
            for (int nt = 0; nt < 4; ++nt)
                for (int r = 0; r < 4; ++r) sfr[nt][r] = 0.f;
            for (int kk = 0; kk < 4; ++kk)
                for (int nt = 0; nt < 4; ++nt) {
                    short8 kf = *(const short8*)
                        &Ks[bi][kk * 2048 + (nt * 16 + l16) * 32 + quad * 8];
                    sfr[nt] = __builtin_amdgcn_mfma_f32_16x16x32_bf16(
                        qf[mt][kk], kf, sfr[nt], 0, 0, 0);
                }

            // ---- scale + causal mask ----
            float sv[4][4];
            const int qg = q0 + wave * 32 + mt * 16 + quad * 4;
            for (int nt = 0; nt < 4; ++nt) {
                const int kgl = k0 + nt * 16 + l16;
                for (int r = 0; r < 4; ++r) {
                    float s = sfr[nt][r] * scale;
                    if (diag && kgl > qg + r) s = -1e30f;
                    sv[nt][r] = s;
                }
            }
            // ---- online softmax ----
            float rmax[4];
            for (int r = 0; r < 4; ++r)
                rmax[r] = fmaxf(fmaxf(sv[0][r], sv[1][r]), fmaxf(sv[2][r], sv[3][r]));
            for (int off = 1; off < 16; off <<= 1)
                for (int r = 0; r < 4; ++r)
                    rmax[r] = fmaxf(rmax[r], __shfl_xor(rmax[r], off));
            float alpha[4];
            for (int r = 0; r < 4; ++r) {
                const float mnew = fmaxf(m_r[mt][r], rmax[r]);
                alpha[r] = __expf(m_r[mt][r] - mnew);
                m_r[mt][r] = mnew;
            }
            float pm[4][4], psum[4];
            for (int r = 0; r < 4; ++r) psum[r] = 0.f;
            for (int nt = 0; nt < 4; ++nt)
                for (int r = 0; r < 4; ++r) {
                    const float p = __expf(sv[nt][r] - m_r[mt][r]);
                    pm[nt][r] = p;
                    psum[r] += p;
                }
            for (int off = 1; off < 16; off <<= 1)
                for (int r = 0; r < 4; ++r)
                    psum[r] += __shfl_xor(psum[r], off);
            for (int r = 0; r < 4; ++r)
                l_r[mt][r] = l_r[mt][r] * alpha[r] + psum[r];
            for (int nt = 0; nt < 8; ++nt)
                for (int r = 0; r < 4; ++r) accO[mt][nt][r] *= alpha[r];

            // ---- P -> LDS (C-layout write, stride 72), re-read in A-layout ----
            for (int nt = 0; nt < 4; ++nt)
                for (int r = 0; r < 4; ++r)
                    Ps[wave][(quad * 4 + r) * 72 + nt * 16 + l16] =
                        __float2bfloat16(pm[nt][r]);
            __builtin_amdgcn_s_waitcnt(0xc07f);   // lgkmcnt(0): own-wave Ps visible

            // ---- O += P V  (Vt reads use the kv-group XOR swizzle) ----
            for (int ks = 0; ks < 2; ++ks) {
                short8 pf = *(const short8*)
                    &Ps[wave][l16 * 72 + ks * 32 + quad * 8];
                for (int nt = 0; nt < 8; ++nt) {
                    const int d = nt * 16 + l16;
                    const int gp = ((ks * 4 + quad) ^ (l16 & 7)) * 8;
                    short8 vf = *(const short8*)&Vt[bi][d * 64 + gp];
                    accO[mt][nt] = __builtin_amdgcn_mfma_f32_16x16x32_bf16(
                        pf, vf, accO[mt][nt], 0, 0, 0);
                }
            }
            __builtin_amdgcn_s_waitcnt(0xc07f);   // pf reads done before next mt rewrite
        }
    }

    bf16* Ob = O + (size_t)b * SS * DD + h * HDD;
    for (int mt = 0; mt < 2; ++mt) {
        float inv[4];
        for (int r = 0; r < 4; ++r) inv[r] = 1.f / l_r[mt][r];
        for (int nt = 0; nt < 8; ++nt)
            for (int r = 0; r < 4; ++r)
                Ob[(size_t)(q0 + wave * 32 + mt * 16 + quad * 4 + r) * DD +
                   nt * 16 + l16] = __float2bfloat16(accO[mt][nt][r] * inv[r]);
    }
}

extern "C" void kernel_launch(void* const* d_in, const int* in_sizes, int n_in,
                              void* d_out, int out_size, void* d_ws, size_t ws_size,
                              hipStream_t stream) {
    (void)in_sizes; (void)n_in; (void)out_size; (void)ws_size;
    const float* x     = (const float*)d_in[0];
    const float* freqs = (const float*)d_in[1];
    // d_in[2] = mask: exactly causal 0/-1e9 -> applied analytically in flash_attn
    const float* Wq    = (const float*)d_in[3];
    const float* Wdown = (const float*)d_in[4];
    const float* Wkup  = (const float*)d_in[5];
    const float* Wvup  = (const float*)d_in[6];
    const float* Wo    = (const float*)d_in[7];
    float* out = (float*)d_out;

    char* ws = (char*)d_ws;
    size_t off = 0;
    auto take = [&](size_t bytes) -> void* {
        void* p = ws + off;
        off += (bytes + 255) & ~(size_t)255;
        return p;
    };
    bf16* xb    = (bf16*)take((size_t)MR * DD * 2);         // 16.8 MB (later: attn)
    bf16* WqdT  = (bf16*)take((size_t)QRS * DD * 2);        // 10.5 MB (later: WoT)
    bf16* WkvT  = (bf16*)take((size_t)2 * DD * LATD * 2);   //  4.2 MB
    bf16* QC    = (bf16*)take((size_t)MR * QRS * 2);        // 21.0 MB [Q 2048 | ckv 512]
    bf16* KVb   = (bf16*)take((size_t)MR * 2 * DD * 2);     // 33.6 MB [tok][K | V]
    bf16* VTg   = (bf16*)take((size_t)BB * NH * HDD * SS * 2); // 16.8 MB (~103 MB total)
    bf16* attn  = xb;      // xb dead after QC gemm
    bf16* WoT   = WqdT;    // WqdT dead after QC gemm

    cast_f32_bf16<<<(MR * DD / 4) / 256, 256, 0, stream>>>(
        (const float4*)x, (ushort4*)xb, MR * DD / 4);

    transpose_cast<<<dim3(DD / 32, DD / 32), 256, 0, stream>>>(Wq, WqdT, DD, DD);
    transpose_cast<<<dim3(LATD / 32, DD / 32), 256, 0, stream>>>(
        Wdown, WqdT + (size_t)DD * DD, DD, LATD);
    transpose_cast<<<dim3(DD / 32, LATD / 32), 256, 0, stream>>>(Wkup, WkvT, LATD, DD);
    transpose_cast<<<dim3(DD / 32, LATD / 32), 256, 0, stream>>>(
        Wvup, WkvT + (size_t)DD * LATD, LATD, DD);

    // [Q | c_kv] = x [Wq | Wdown]   (M=4096, N=2560, K=2048)
    gemm_bt<false><<<dim3(QRS / 128, MR / 128), 256, 0, stream>>>(
        xb, WqdT, QC, MR, QRS, DD, DD, DD, QRS);
    // [K | V] = c_kv [Wkup | Wvup]  (M=4096, N=4096, K=512)
    gemm_bt<false><<<dim3(2 * DD / 128, MR / 128), 256, 0, stream>>>(
        QC + DD, WkvT, KVb, MR, 2 * DD, LATD, QRS, LATD, 2 * DD);

    transpose_v<<<dim3(SS / 64, HDD / 64, BB * NH), 256, 0, stream>>>(KVb, VTg);

    rope_qk<<<(MR * NH * 16) / 256, 256, 0, stream>>>(QC, KVb, freqs, MR * NH * 16);

    flash_attn<<<dim3(SS / 128, NH, BB), 256, 0, stream>>>(QC, KVb, VTg, attn);

    // out = attn Wo (fp32 epilogue straight to d_out)
    transpose_cast<<<dim3(DD / 32, DD / 32), 256, 0, stream>>>(Wo, WoT, DD, DD);
    gemm_bt<true><<<dim3(DD / 128, MR / 128), 256, 0, stream>>>(
        attn, WoT, out, MR, DD, DD, DD, DD, DD);
}

// Round 4
// 471.422 us; speedup vs baseline: 1.4389x; 1.0229x over previous
//
#include <hip/hip_runtime.h>
#include <hip/hip_bf16.h>
#include <math.h>

typedef __hip_bfloat16 bf16;
typedef __attribute__((ext_vector_type(8))) short short8;   // 8 x bf16 bits (4 VGPRs)
typedef __attribute__((ext_vector_type(4))) float f32x4;

static constexpr int BB   = 2;
static constexpr int SS   = 2048;
static constexpr int DD   = 2048;
static constexpr int NH   = 16;
static constexpr int HDD  = 128;
static constexpr int LATD = 512;
static constexpr int MR   = BB * SS;   // 4096 token rows
static constexpr int QRS  = DD + LATD; // 2560: row stride of merged [Q | c_kv] buffer

#if __has_builtin(__builtin_amdgcn_exp2f)
#define EXP2F(x) __builtin_amdgcn_exp2f(x)
#else
#define EXP2F(x) exp2f(x)
#endif

__device__ __forceinline__ void async_cp16(const void* g, void* l) {
    __builtin_amdgcn_global_load_lds(
        (const __attribute__((address_space(1))) void*)g,
        (__attribute__((address_space(3))) void*)l, 16, 0, 0);
}

__device__ __forceinline__ unsigned short bf_bits(bf16 v) {
    union { bf16 b; unsigned short u; } cv; cv.b = v; return cv.u;
}

// ---------------- cast f32 -> bf16, vectorized x4 ----------------
__global__ void cast_f32_bf16(const float4* __restrict__ in,
                              ushort4* __restrict__ out, int n4) {
    int i = blockIdx.x * blockDim.x + threadIdx.x;
    if (i >= n4) return;
    float4 v = in[i];
    ushort4 o;
    o.x = bf_bits(__float2bfloat16(v.x));
    o.y = bf_bits(__float2bfloat16(v.y));
    o.z = bf_bits(__float2bfloat16(v.z));
    o.w = bf_bits(__float2bfloat16(v.w));
    out[i] = o;
}

// ---------- transpose + cast: in[rows][cols] f32 -> out[cols][rows] bf16 ----------
__global__ void transpose_cast(const float* __restrict__ in,
                               bf16* __restrict__ out, int rows, int cols) {
    __shared__ float tile[32][33];
    int tx = threadIdx.x & 31, ty = threadIdx.x >> 5;   // 32 x 8 threads
    int c0 = blockIdx.x * 32, r0 = blockIdx.y * 32;
    for (int i = 0; i < 32; i += 8)
        tile[ty + i][tx] = in[(size_t)(r0 + ty + i) * cols + c0 + tx];
    __syncthreads();
    for (int i = 0; i < 32; i += 8)
        out[(size_t)(c0 + ty + i) * rows + r0 + tx] =
            __float2bfloat16(tile[tx][ty + i]);
}

// ---- V pre-transpose: VT[bh][d][s] (bf16) from KV's V half, kv-group XOR swizzle ----
__global__ void transpose_v(const bf16* __restrict__ KV, bf16* __restrict__ VT) {
    __shared__ bf16 t[64][74];
    const int tid = threadIdx.x;
    const int s0 = blockIdx.x * 64, d0 = blockIdx.y * 64;
    const int bh = blockIdx.z, b = bh >> 4, h = bh & 15;
    const bf16* src = KV + (size_t)b * SS * 4096 + 2048 + h * 128 + d0;
    for (int p = 0; p < 2; ++p) {
        const int s = p * 32 + (tid >> 3), dc = (tid & 7) * 8;
        short8 v = *(const short8*)(src + (size_t)(s0 + s) * 4096 + dc);
        const bf16* ve = (const bf16*)&v;
        for (int e = 0; e < 8; ++e) t[s][dc + e] = ve[e];
    }
    __syncthreads();
    bf16* dst = VT + ((size_t)bh * HDD + d0) * SS + s0;
    for (int p = 0; p < 2; ++p) {
        const int d = p * 32 + (tid >> 3), g = tid & 7;
        short8 v; bf16* ve = (bf16*)&v;
        for (int e = 0; e < 8; ++e) ve[e] = t[g * 8 + e][d];
        const int gp = g ^ (d & 7);
        *(short8*)(dst + (size_t)d * SS + gp * 8) = v;
    }
}

// ------- double-buffered GEMM: C[M][N] = A[M][K(lda)] * Bt[N][K(ldb)]^T -------
template <bool OUT_F32>
__global__ __launch_bounds__(256) void gemm_bt(
    const bf16* __restrict__ A, const bf16* __restrict__ Bt,
    void* __restrict__ Cout, int M, int N, int K, int lda, int ldb, int ldc) {
    __shared__ bf16 As[2][128 * 32];
    __shared__ bf16 Bs[2][128 * 32];
    const int tid  = threadIdx.x;
    const int lane = tid & 63, wave = tid >> 6;
    const int quad = lane >> 4, l16 = lane & 15;
    const int row0 = blockIdx.y * 128, col0 = blockIdx.x * 128;
    const int wm = (wave >> 1) * 64, wn = (wave & 1) * 64;
    const int srow = lane >> 2;
    const int scol = (lane & 3) * 8;

    f32x4 acc[4][4];
    for (int i = 0; i < 4; ++i)
        for (int j = 0; j < 4; ++j)
            for (int r = 0; r < 4; ++r) acc[i][j][r] = 0.f;

    auto stage = [&](int k0, int bufi) {
        for (int c = 0; c < 2; ++c) {
            const int chunk = wave * 2 + c;
            const int r = chunk * 16 + srow;
            async_cp16(A  + (size_t)(row0 + r) * lda + k0 + scol, &As[bufi][chunk * 512]);
            async_cp16(Bt + (size_t)(col0 + r) * ldb + k0 + scol, &Bs[bufi][chunk * 512]);
        }
    };

    const int nk = K / 32;
    stage(0, 0);
    for (int ki = 0; ki < nk; ++ki) {
        __syncthreads();                    // drains stage ki; frees buf (ki+1)&1
        if (ki + 1 < nk) stage((ki + 1) * 32, (ki + 1) & 1);
        const int bi = ki & 1;
        short8 af[4], bfr[4];
        for (int t = 0; t < 4; ++t) {
            af[t]  = *(const short8*)&As[bi][(wm + t * 16 + l16) * 32 + quad * 8];
            bfr[t] = *(const short8*)&Bs[bi][(wn + t * 16 + l16) * 32 + quad * 8];
        }
        for (int i = 0; i < 4; ++i)
            for (int j = 0; j < 4; ++j)
                acc[i][j] = __builtin_amdgcn_mfma_f32_16x16x32_bf16(
                    af[i], bfr[j], acc[i][j], 0, 0, 0);
    }

    const int rbase = row0 + wm + quad * 4;
    const int cbase = col0 + wn + l16;
    if (OUT_F32) {
        float* C = (float*)Cout;
        for (int i = 0; i < 4; ++i)
            for (int j = 0; j < 4; ++j)
                for (int r = 0; r < 4; ++r)
                    C[(size_t)(rbase + i * 16 + r) * ldc + cbase + j * 16] = acc[i][j][r];
    } else {
        bf16* C = (bf16*)Cout;
        for (int i = 0; i < 4; ++i)
            for (int j = 0; j < 4; ++j)
                for (int r = 0; r < 4; ++r)
                    C[(size_t)(rbase + i * 16 + r) * ldc + cbase + j * 16] =
                        __float2bfloat16(acc[i][j][r]);
    }
}

// ------- RoPE on Q (stride 2560, pre-scaled by 1/sqrt(HD)*log2e) and K (stride 4096) -------
__global__ void rope_qk(bf16* __restrict__ Q, bf16* __restrict__ KV,
                        const float* __restrict__ freqs, int n) {
    const float QS = 0.08838834764831845f * 1.4426950408889634f;  // scale * log2(e)
    int idx = blockIdx.x * blockDim.x + threadIdx.x;
    if (idx >= n) return;
    const int pg  = idx & 15;
    const int h   = (idx >> 4) & (NH - 1);
    const int tok = idx >> 8;
    const int s   = tok & (SS - 1);
    const float4 f = *(const float4*)&freqs[s * 64 + pg * 4];
    float cs[4], sn[4];
    cs[0] = __cosf(f.x); sn[0] = __sinf(f.x);
    cs[1] = __cosf(f.y); sn[1] = __sinf(f.y);
    cs[2] = __cosf(f.z); sn[2] = __sinf(f.z);
    cs[3] = __cosf(f.w); sn[3] = __sinf(f.w);

    bf16* qp = Q  + (size_t)tok * QRS  + h * HDD + pg * 8;
    bf16* kp = KV + (size_t)tok * 4096 + h * HDD + pg * 8;
    for (int pass = 0; pass < 2; ++pass) {
        bf16* p = pass ? kp : qp;
        const float g = pass ? 1.f : QS;
        short8 v = *(const short8*)p;
        const bf16* ve = (const bf16*)&v;
        short8 o;
        bf16* oe = (bf16*)&o;
        for (int i = 0; i < 4; ++i) {
            float t0 = __bfloat162float(ve[2 * i]);
            float t1 = __bfloat162float(ve[2 * i + 1]);
            oe[2 * i]     = __float2bfloat16((t0 * cs[i] - t1 * sn[i]) * g);
            oe[2 * i + 1] = __float2bfloat16((t0 * sn[i] + t1 * cs[i]) * g);
        }
        *(short8*)p = o;
    }
}

// ------------- causal flash attention, BQ=128, BKV=64, double-buffered -------------
// 1D grid 512, work-balanced mapping: pair p=j>>1 -> bh=p>>3, m=p&7,
// qt = (j&1) ? m : 15-m  (consecutive blocks are complementary in work).
// 256 thr = 4 waves; wave w: q rows [w*32, w*32+32) as 2 m-tiles of 16.
__global__ __launch_bounds__(256) void flash_attn(
    const bf16* __restrict__ QC, const bf16* __restrict__ KV,
    const bf16* __restrict__ VTg, bf16* __restrict__ O) {
    const int j = blockIdx.x;
    const int pr = j >> 1, mm = pr & 7, bh = pr >> 3;
    const int qt = (j & 1) ? mm : 15 - mm;
    const int h = bh & (NH - 1), b = bh >> 4;
    const int q0 = qt * 128;
    const int tid = threadIdx.x, lane = tid & 63, wave = tid >> 6;
    const int quad = lane >> 4, l16 = lane & 15;

    __shared__ bf16 Ks[2][4 * 64 * 32];   // 2 x 16 KB, [kk][r][32]
    __shared__ bf16 Vt[2][128 * 64];      // 2 x 16 KB, [d][64] (kv-group swizzled)
    __shared__ bf16 Ps[4][16 * 72];       // 9 KB, shared across m-tiles

    const bf16* Kb  = KV  + (size_t)b * SS * 4096 + h * HDD;
    const bf16* VTb = VTg + (size_t)bh * HDD * SS;
    const int krs = 4096;

    // Q A-frags: 2 m-tiles x 4 k-steps (Q pre-scaled by 1/sqrt(HD)*log2e in rope)
    short8 qf[2][4];
    for (int mt = 0; mt < 2; ++mt) {
        const bf16* qrow = QC + (size_t)(b * SS + q0 + wave * 32 + mt * 16 + l16) * QRS
                              + h * HDD;
        for (int kk = 0; kk < 4; ++kk)
            qf[mt][kk] = *(const short8*)(qrow + kk * 32 + quad * 8);
    }

    auto stage = [&](int kt, int bufi) {
        const int k0 = kt * 64;
        for (int i = 0; i < 4; ++i)
            async_cp16(Kb + (size_t)(k0 + i * 16 + (lane >> 2)) * krs
                           + wave * 32 + (lane & 3) * 8,
                       &Ks[bufi][wave * 2048 + i * 512]);
        for (int c2 = 0; c2 < 4; ++c2) {
            const int c = wave * 4 + c2;
            async_cp16(VTb + (size_t)(c * 8 + (lane >> 3)) * SS + k0 + (lane & 7) * 8,
                       &Vt[bufi][c * 512]);
        }
    };

    f32x4 accO[2][8];
    for (int mt = 0; mt < 2; ++mt)
        for (int i = 0; i < 8; ++i)
            for (int r = 0; r < 4; ++r) accO[mt][i][r] = 0.f;
    float m_r[2][4], l_r[2][4];
    for (int mt = 0; mt < 2; ++mt)
        for (int r = 0; r < 4; ++r) { m_r[mt][r] = -1e30f; l_r[mt][r] = 0.f; }

    const int ktMax = 2 * qt + 1;

    stage(0, 0);
    for (int kt = 0; kt <= ktMax; ++kt) {
        const int k0 = kt * 64;
        __syncthreads();                    // drains stage kt; frees buf (kt+1)&1
        if (kt < ktMax) stage(kt + 1, (kt + 1) & 1);
        const int bi = kt & 1;

        // ---- S = Q K^T for BOTH m-tiles, sharing each K frag ----
        f32x4 sfr[2][4];
        for (int mt = 0; mt < 2; ++mt)
            for (int nt = 0; nt < 4; ++nt)
                for (int r = 0; r < 4; ++r) sfr[mt][nt][r] = 0.f;
        for (int kk = 0; kk < 4; ++kk)
            for (int nt = 0; nt < 4; ++nt) {
                short8 kf = *(const short8*)
                    &Ks[bi][kk * 2048 + (nt * 16 + l16) * 32 + quad * 8];
                sfr[0][nt] = __builtin_amdgcn_mfma_f32_16x16x32_bf16(
                    qf[0][kk], kf, sfr[0][nt], 0, 0, 0);
                sfr[1][nt] = __builtin_amdgcn_mfma_f32_16x16x32_bf16(
                    qf[1][kk], kf, sfr[1][nt], 0, 0, 0);
            }

        const bool diag = (kt >= 2 * qt);
        for (int mt = 0; mt < 2; ++mt) {
            // ---- causal mask (S already scaled; log2 domain) ----
            float sv[4][4];
            const int qg = q0 + wave * 32 + mt * 16 + quad * 4;
            for (int nt = 0; nt < 4; ++nt) {
                const int kgl = k0 + nt * 16 + l16;
                for (int r = 0; r < 4; ++r) {
                    float s = sfr[mt][nt][r];
                    if (diag && kgl > qg + r) s = -1e30f;
                    sv[nt][r] = s;
                }
            }
            // ---- online softmax in exp2 domain ----
            float rmax[4];
            for (int r = 0; r < 4; ++r)
                rmax[r] = fmaxf(fmaxf(sv[0][r], sv[1][r]), fmaxf(sv[2][r], sv[3][r]));
            for (int off = 1; off < 16; off <<= 1)
                for (int r = 0; r < 4; ++r)
                    rmax[r] = fmaxf(rmax[r], __shfl_xor(rmax[r], off));
            float alpha[4];
            for (int r = 0; r < 4; ++r) {
                const float mnew = fmaxf(m_r[mt][r], rmax[r]);
                alpha[r] = EXP2F(m_r[mt][r] - mnew);
                m_r[mt][r] = mnew;
            }
            float pm[4][4], psum[4];
            for (int r = 0; r < 4; ++r) psum[r] = 0.f;
            for (int nt = 0; nt < 4; ++nt)
                for (int r = 0; r < 4; ++r) {
                    const float p = EXP2F(sv[nt][r] - m_r[mt][r]);
                    pm[nt][r] = p;
                    psum[r] += p;
                }
            for (int off = 1; off < 16; off <<= 1)
                for (int r = 0; r < 4; ++r)
                    psum[r] += __shfl_xor(psum[r], off);
            for (int r = 0; r < 4; ++r)
                l_r[mt][r] = l_r[mt][r] * alpha[r] + psum[r];
            for (int nt = 0; nt < 8; ++nt)
                for (int r = 0; r < 4; ++r) accO[mt][nt][r] *= alpha[r];

            // ---- P -> LDS (C-layout write, stride 72), re-read in A-layout ----
            for (int nt = 0; nt < 4; ++nt)
                for (int r = 0; r < 4; ++r)
                    Ps[wave][(quad * 4 + r) * 72 + nt * 16 + l16] =
                        __float2bfloat16(pm[nt][r]);
            __builtin_amdgcn_s_waitcnt(0xc07f);   // lgkmcnt(0): own-wave Ps visible

            // ---- O += P V  (Vt reads use the kv-group XOR swizzle) ----
            for (int ks = 0; ks < 2; ++ks) {
                short8 pf = *(const short8*)
                    &Ps[wave][l16 * 72 + ks * 32 + quad * 8];
                for (int nt = 0; nt < 8; ++nt) {
                    const int d = nt * 16 + l16;
                    const int gp = ((ks * 4 + quad) ^ (l16 & 7)) * 8;
                    short8 vf = *(const short8*)&Vt[bi][d * 64 + gp];
                    accO[mt][nt] = __builtin_amdgcn_mfma_f32_16x16x32_bf16(
                        pf, vf, accO[mt][nt], 0, 0, 0);
                }
            }
            __builtin_amdgcn_s_waitcnt(0xc07f);   // pf reads done before next mt rewrite
        }
    }

    bf16* Ob = O + (size_t)b * SS * DD + h * HDD;
    for (int mt = 0; mt < 2; ++mt) {
        float inv[4];
        for (int r = 0; r < 4; ++r) inv[r] = 1.f / l_r[mt][r];
        for (int nt = 0; nt < 8; ++nt)
            for (int r = 0; r < 4; ++r)
                Ob[(size_t)(q0 + wave * 32 + mt * 16 + quad * 4 + r) * DD +
                   nt * 16 + l16] = __float2bfloat16(accO[mt][nt][r] * inv[r]);
    }
}

extern "C" void kernel_launch(void* const* d_in, const int* in_sizes, int n_in,
                              void* d_out, int out_size, void* d_ws, size_t ws_size,
                              hipStream_t stream) {
    (void)in_sizes; (void)n_in; (void)out_size; (void)ws_size;
    const float* x     = (const float*)d_in[0];
    const float* freqs = (const float*)d_in[1];
    // d_in[2] = mask: exactly causal 0/-1e9 -> applied analytically in flash_attn
    const float* Wq    = (const float*)d_in[3];
    const float* Wdown = (const float*)d_in[4];
    const float* Wkup  = (const float*)d_in[5];
    const float* Wvup  = (const float*)d_in[6];
    const float* Wo    = (const float*)d_in[7];
    float* out = (float*)d_out;

    char* ws = (char*)d_ws;
    size_t off = 0;
    auto take = [&](size_t bytes) -> void* {
        void* p = ws + off;
        off += (bytes + 255) & ~(size_t)255;
        return p;
    };
    bf16* xb    = (bf16*)take((size_t)MR * DD * 2);         // 16.8 MB (later: attn)
    bf16* WqdT  = (bf16*)take((size_t)QRS * DD * 2);        // 10.5 MB (later: WoT)
    bf16* WkvT  = (bf16*)take((size_t)2 * DD * LATD * 2);   //  4.2 MB
    bf16* QC    = (bf16*)take((size_t)MR * QRS * 2);        // 21.0 MB [Q 2048 | ckv 512]
    bf16* KVb   = (bf16*)take((size_t)MR * 2 * DD * 2);     // 33.6 MB [tok][K | V]
    bf16* VTg   = (bf16*)take((size_t)BB * NH * HDD * SS * 2); // 16.8 MB (~103 MB total)
    bf16* attn  = xb;      // xb dead after QC gemm
    bf16* WoT   = WqdT;    // WqdT dead after QC gemm

    cast_f32_bf16<<<(MR * DD / 4) / 256, 256, 0, stream>>>(
        (const float4*)x, (ushort4*)xb, MR * DD / 4);

    transpose_cast<<<dim3(DD / 32, DD / 32), 256, 0, stream>>>(Wq, WqdT, DD, DD);
    transpose_cast<<<dim3(LATD / 32, DD / 32), 256, 0, stream>>>(
        Wdown, WqdT + (size_t)DD * DD, DD, LATD);
    transpose_cast<<<dim3(DD / 32, LATD / 32), 256, 0, stream>>>(Wkup, WkvT, LATD, DD);
    transpose_cast<<<dim3(DD / 32, LATD / 32), 256, 0, stream>>>(
        Wvup, WkvT + (size_t)DD * LATD, LATD, DD);

    // [Q | c_kv] = x [Wq | Wdown]   (M=4096, N=2560, K=2048)
    gemm_bt<false><<<dim3(QRS / 128, MR / 128), 256, 0, stream>>>(
        xb, WqdT, QC, MR, QRS, DD, DD, DD, QRS);
    // [K | V] = c_kv [Wkup | Wvup]  (M=4096, N=4096, K=512)
    gemm_bt<false><<<dim3(2 * DD / 128, MR / 128), 256, 0, stream>>>(
        QC + DD, WkvT, KVb, MR, 2 * DD, LATD, QRS, LATD, 2 * DD);

    transpose_v<<<dim3(SS / 64, HDD / 64, BB * NH), 256, 0, stream>>>(KVb, VTg);

    rope_qk<<<(MR * NH * 16) / 256, 256, 0, stream>>>(QC, KVb, freqs, MR * NH * 16);

    flash_attn<<<512, 256, 0, stream>>>(QC, KVb, VTg, attn);

    // out = attn Wo (fp32 epilogue straight to d_out)
    transpose_cast<<<dim3(DD / 32, DD / 32), 256, 0, stream>>>(Wo, WoT, DD, DD);
    gemm_bt<true><<<dim3(DD / 128, MR / 128), 256, 0, stream>>>(
        attn, WoT, out, MR, DD, DD, DD, DD, DD);
}

// Round 5
// 441.632 us; speedup vs baseline: 1.5359x; 1.0675x over previous
//
#include <hip/hip_runtime.h>
#include <hip/hip_bf16.h>
#include <math.h>

typedef __hip_bfloat16 bf16;
typedef __attribute__((ext_vector_type(8))) short short8;   // 8 x bf16 bits (4 VGPRs)
typedef __attribute__((ext_vector_type(4))) float f32x4;

static constexpr int BB   = 2;
static constexpr int SS   = 2048;
static constexpr int DD   = 2048;
static constexpr int NH   = 16;
static constexpr int HDD  = 128;
static constexpr int LATD = 512;
static constexpr int MR   = BB * SS;   // 4096 token rows
static constexpr int QRS  = DD + LATD; // 2560: row stride of merged [Q | c_kv] buffer

#if __has_builtin(__builtin_amdgcn_exp2f)
#define EXP2F(x) __builtin_amdgcn_exp2f(x)
#else
#define EXP2F(x) exp2f(x)
#endif

__device__ __forceinline__ void async_cp16(const void* g, void* l) {
    __builtin_amdgcn_global_load_lds(
        (const __attribute__((address_space(1))) void*)g,
        (__attribute__((address_space(3))) void*)l, 16, 0, 0);
}

__device__ __forceinline__ unsigned short bf_bits(bf16 v) {
    union { bf16 b; unsigned short u; } cv; cv.b = v; return cv.u;
}

// ---------------- cast f32 -> bf16, vectorized x4 ----------------
__global__ void cast_f32_bf16(const float4* __restrict__ in,
                              ushort4* __restrict__ out, int n4) {
    int i = blockIdx.x * blockDim.x + threadIdx.x;
    if (i >= n4) return;
    float4 v = in[i];
    ushort4 o;
    o.x = bf_bits(__float2bfloat16(v.x));
    o.y = bf_bits(__float2bfloat16(v.y));
    o.z = bf_bits(__float2bfloat16(v.z));
    o.w = bf_bits(__float2bfloat16(v.w));
    out[i] = o;
}

// ---------- transpose + cast: in[rows][cols] f32 -> out[cols][rows] bf16 ----------
__global__ void transpose_cast(const float* __restrict__ in,
                               bf16* __restrict__ out, int rows, int cols) {
    __shared__ float tile[32][33];
    int tx = threadIdx.x & 31, ty = threadIdx.x >> 5;   // 32 x 8 threads
    int c0 = blockIdx.x * 32, r0 = blockIdx.y * 32;
    for (int i = 0; i < 32; i += 8)
        tile[ty + i][tx] = in[(size_t)(r0 + ty + i) * cols + c0 + tx];
    __syncthreads();
    for (int i = 0; i < 32; i += 8)
        out[(size_t)(c0 + ty + i) * rows + r0 + tx] =
            __float2bfloat16(tile[tx][ty + i]);
}

// ---- V pre-transpose: VT[bh][d][s] (bf16) from KV's V half, kv-group XOR swizzle ----
__global__ void transpose_v(const bf16* __restrict__ KV, bf16* __restrict__ VT) {
    __shared__ bf16 t[64][74];
    const int tid = threadIdx.x;
    const int s0 = blockIdx.x * 64, d0 = blockIdx.y * 64;
    const int bh = blockIdx.z, b = bh >> 4, h = bh & 15;
    const bf16* src = KV + (size_t)b * SS * 4096 + 2048 + h * 128 + d0;
    for (int p = 0; p < 2; ++p) {
        const int s = p * 32 + (tid >> 3), dc = (tid & 7) * 8;
        short8 v = *(const short8*)(src + (size_t)(s0 + s) * 4096 + dc);
        const bf16* ve = (const bf16*)&v;
        for (int e = 0; e < 8; ++e) t[s][dc + e] = ve[e];
    }
    __syncthreads();
    bf16* dst = VT + ((size_t)bh * HDD + d0) * SS + s0;
    for (int p = 0; p < 2; ++p) {
        const int d = p * 32 + (tid >> 3), g = tid & 7;
        short8 v; bf16* ve = (bf16*)&v;
        for (int e = 0; e < 8; ++e) ve[e] = t[g * 8 + e][d];
        const int gp = g ^ (d & 7);
        *(short8*)(dst + (size_t)d * SS + gp * 8) = v;
    }
}

// ------- double-buffered GEMM: C[M][N] = A[M][K(lda)] * Bt[N][K(ldb)]^T -------
template <bool OUT_F32>
__global__ __launch_bounds__(256) void gemm_bt(
    const bf16* __restrict__ A, const bf16* __restrict__ Bt,
    void* __restrict__ Cout, int M, int N, int K, int lda, int ldb, int ldc) {
    __shared__ bf16 As[2][128 * 32];
    __shared__ bf16 Bs[2][128 * 32];
    const int tid  = threadIdx.x;
    const int lane = tid & 63, wave = tid >> 6;
    const int quad = lane >> 4, l16 = lane & 15;
    const int row0 = blockIdx.y * 128, col0 = blockIdx.x * 128;
    const int wm = (wave >> 1) * 64, wn = (wave & 1) * 64;
    const int srow = lane >> 2;
    const int scol = (lane & 3) * 8;

    f32x4 acc[4][4];
    for (int i = 0; i < 4; ++i)
        for (int j = 0; j < 4; ++j)
            for (int r = 0; r < 4; ++r) acc[i][j][r] = 0.f;

    auto stage = [&](int k0, int bufi) {
        for (int c = 0; c < 2; ++c) {
            const int chunk = wave * 2 + c;
            const int r = chunk * 16 + srow;
            async_cp16(A  + (size_t)(row0 + r) * lda + k0 + scol, &As[bufi][chunk * 512]);
            async_cp16(Bt + (size_t)(col0 + r) * ldb + k0 + scol, &Bs[bufi][chunk * 512]);
        }
    };

    const int nk = K / 32;
    stage(0, 0);
    for (int ki = 0; ki < nk; ++ki) {
        __syncthreads();                    // drains stage ki; frees buf (ki+1)&1
        if (ki + 1 < nk) stage((ki + 1) * 32, (ki + 1) & 1);
        const int bi = ki & 1;
        short8 af[4], bfr[4];
        for (int t = 0; t < 4; ++t) {
            af[t]  = *(const short8*)&As[bi][(wm + t * 16 + l16) * 32 + quad * 8];
            bfr[t] = *(const short8*)&Bs[bi][(wn + t * 16 + l16) * 32 + quad * 8];
        }
        for (int i = 0; i < 4; ++i)
            for (int j = 0; j < 4; ++j)
                acc[i][j] = __builtin_amdgcn_mfma_f32_16x16x32_bf16(
                    af[i], bfr[j], acc[i][j], 0, 0, 0);
    }

    const int rbase = row0 + wm + quad * 4;
    const int cbase = col0 + wn + l16;
    if (OUT_F32) {
        float* C = (float*)Cout;
        for (int i = 0; i < 4; ++i)
            for (int j = 0; j < 4; ++j)
                for (int r = 0; r < 4; ++r)
                    C[(size_t)(rbase + i * 16 + r) * ldc + cbase + j * 16] = acc[i][j][r];
    } else {
        bf16* C = (bf16*)Cout;
        for (int i = 0; i < 4; ++i)
            for (int j = 0; j < 4; ++j)
                for (int r = 0; r < 4; ++r)
                    C[(size_t)(rbase + i * 16 + r) * ldc + cbase + j * 16] =
                        __float2bfloat16(acc[i][j][r]);
    }
}

// ------- RoPE on Q (stride 2560, pre-scaled by 1/sqrt(HD)*log2e) and K (stride 4096) -------
__global__ void rope_qk(bf16* __restrict__ Q, bf16* __restrict__ KV,
                        const float* __restrict__ freqs, int n) {
    const float QS = 0.08838834764831845f * 1.4426950408889634f;  // scale * log2(e)
    int idx = blockIdx.x * blockDim.x + threadIdx.x;
    if (idx >= n) return;
    const int pg  = idx & 15;
    const int h   = (idx >> 4) & (NH - 1);
    const int tok = idx >> 8;
    const int s   = tok & (SS - 1);
    const float4 f = *(const float4*)&freqs[s * 64 + pg * 4];
    float cs[4], sn[4];
    cs[0] = __cosf(f.x); sn[0] = __sinf(f.x);
    cs[1] = __cosf(f.y); sn[1] = __sinf(f.y);
    cs[2] = __cosf(f.z); sn[2] = __sinf(f.z);
    cs[3] = __cosf(f.w); sn[3] = __sinf(f.w);

    bf16* qp = Q  + (size_t)tok * QRS  + h * HDD + pg * 8;
    bf16* kp = KV + (size_t)tok * 4096 + h * HDD + pg * 8;
    for (int pass = 0; pass < 2; ++pass) {
        bf16* p = pass ? kp : qp;
        const float g = pass ? 1.f : QS;
        short8 v = *(const short8*)p;
        const bf16* ve = (const bf16*)&v;
        short8 o;
        bf16* oe = (bf16*)&o;
        for (int i = 0; i < 4; ++i) {
            float t0 = __bfloat162float(ve[2 * i]);
            float t1 = __bfloat162float(ve[2 * i + 1]);
            oe[2 * i]     = __float2bfloat16((t0 * cs[i] - t1 * sn[i]) * g);
            oe[2 * i + 1] = __float2bfloat16((t0 * sn[i] + t1 * cs[i]) * g);
        }
        *(short8*)p = o;
    }
}

// ------------- causal flash attention, BQ=128, BKV=64, double-buffered -------------
// 1D grid 512, balanced mapping; 512 threads = 8 waves; wave w owns q rows
// [q0 + w*16, +16) (one m-tile). LDS = exactly 80 KB -> 2 blocks/CU = 4 waves/SIMD.
//   Ks[2][kk=4][r=64][32]   32 KB
//   Vt[2][d=128][64]        32 KB (kv-group XOR swizzled in global already)
//   Ps[8][16][64]           16 KB (group-XOR swizzle: g stored at g^(row&7))
__global__ __launch_bounds__(512, 4) void flash_attn(
    const bf16* __restrict__ QC, const bf16* __restrict__ KV,
    const bf16* __restrict__ VTg, bf16* __restrict__ O) {
    const int j = blockIdx.x;
    const int pr = j >> 1, mm = pr & 7, bh = pr >> 3;
    const int qt = (j & 1) ? mm : 15 - mm;
    const int h = bh & (NH - 1), b = bh >> 4;
    const int q0 = qt * 128;
    const int tid = threadIdx.x, lane = tid & 63, wave = tid >> 6;
    const int quad = lane >> 4, l16 = lane & 15;

    __shared__ char smem[81920];
    bf16* KsB = (bf16*)smem;              // [2][8192]
    bf16* VtB = (bf16*)(smem + 32768);    // [2][8192]
    bf16* PsB = (bf16*)(smem + 65536);    // [8][1024]

    const bf16* Kb  = KV  + (size_t)b * SS * 4096 + h * HDD;
    const bf16* VTb = VTg + (size_t)bh * HDD * SS;
    const int krs = 4096;

    // Q A-frags: 4 k-steps (Q pre-scaled by 1/sqrt(HD)*log2e in rope)
    short8 qf[4];
    {
        const bf16* qrow = QC + (size_t)(b * SS + q0 + wave * 16 + l16) * QRS + h * HDD;
        for (int kk = 0; kk < 4; ++kk)
            qf[kk] = *(const short8*)(qrow + kk * 32 + quad * 8);
    }

    auto stage = [&](int kt, int bufi) {
        const int k0 = kt * 64;
        // K tile [64][128] -> Ks[kk][r][32]; wave covers kk=wave>>1, rows half=(wave&1)*32
        const int kk = wave >> 1, half = wave & 1;
        for (int i = 0; i < 2; ++i) {
            const int rbase = half * 32 + i * 16;
            async_cp16(Kb + (size_t)(k0 + rbase + (lane >> 2)) * krs
                           + kk * 32 + (lane & 3) * 8,
                       &KsB[bufi * 8192 + kk * 2048 + rbase * 32]);
        }
        // V^T tile: chunk c = 8 d-rows x 64 s (1 KB); wave covers c = wave*2 + c2
        for (int c2 = 0; c2 < 2; ++c2) {
            const int c = wave * 2 + c2;
            async_cp16(VTb + (size_t)(c * 8 + (lane >> 3)) * SS + k0 + (lane & 7) * 8,
                       &VtB[bufi * 8192 + c * 512]);
        }
    };

    f32x4 accO[8];
    for (int i = 0; i < 8; ++i)
        for (int r = 0; r < 4; ++r) accO[i][r] = 0.f;
    float m_r[4], l_r[4];
    for (int r = 0; r < 4; ++r) { m_r[r] = -1e30f; l_r[r] = 0.f; }

    const int ktMax = 2 * qt + 1;

    stage(0, 0);
    for (int kt = 0; kt <= ktMax; ++kt) {
        const int k0 = kt * 64;
        __syncthreads();                    // drains stage kt; frees buf (kt+1)&1
        if (kt < ktMax) stage(kt + 1, (kt + 1) & 1);
        const int bi = kt & 1;

        // ---- S = Q K^T : [16 q][64 k] ----
        f32x4 sfr[4];
        for (int nt = 0; nt < 4; ++nt)
            for (int r = 0; r < 4; ++r) sfr[nt][r] = 0.f;
        for (int kk = 0; kk < 4; ++kk)
            for (int nt = 0; nt < 4; ++nt) {
                short8 kf = *(const short8*)
                    &KsB[bi * 8192 + kk * 2048 + (nt * 16 + l16) * 32 + quad * 8];
                sfr[nt] = __builtin_amdgcn_mfma_f32_16x16x32_bf16(
                    qf[kk], kf, sfr[nt], 0, 0, 0);
            }

        // ---- causal mask (S already scaled; log2 domain) ----
        float sv[4][4];
        const bool diag = (kt >= 2 * qt);
        const int qg = q0 + wave * 16 + quad * 4;
        for (int nt = 0; nt < 4; ++nt) {
            const int kgl = k0 + nt * 16 + l16;
            for (int r = 0; r < 4; ++r) {
                float s = sfr[nt][r];
                if (diag && kgl > qg + r) s = -1e30f;
                sv[nt][r] = s;
            }
        }
        // ---- online softmax in exp2 domain ----
        float rmax[4];
        for (int r = 0; r < 4; ++r)
            rmax[r] = fmaxf(fmaxf(sv[0][r], sv[1][r]), fmaxf(sv[2][r], sv[3][r]));
        for (int off = 1; off < 16; off <<= 1)
            for (int r = 0; r < 4; ++r)
                rmax[r] = fmaxf(rmax[r], __shfl_xor(rmax[r], off));
        float alpha[4];
        for (int r = 0; r < 4; ++r) {
            const float mnew = fmaxf(m_r[r], rmax[r]);
            alpha[r] = EXP2F(m_r[r] - mnew);
            m_r[r] = mnew;
        }
        float psum[4];
        for (int r = 0; r < 4; ++r) psum[r] = 0.f;
        for (int nt = 0; nt < 4; ++nt)
            for (int r = 0; r < 4; ++r) {
                const float p = EXP2F(sv[nt][r] - m_r[r]);
                sv[nt][r] = p;                 // reuse regs: sv becomes P
                psum[r] += p;
            }
        for (int off = 1; off < 16; off <<= 1)
            for (int r = 0; r < 4; ++r)
                psum[r] += __shfl_xor(psum[r], off);
        for (int r = 0; r < 4; ++r)
            l_r[r] = l_r[r] * alpha[r] + psum[r];
        for (int nt = 0; nt < 8; ++nt)
            for (int r = 0; r < 4; ++r) accO[nt][r] *= alpha[r];

        // ---- P -> LDS (C-layout write, group-XOR swizzle), re-read in A-layout ----
        for (int nt = 0; nt < 4; ++nt)
            for (int r = 0; r < 4; ++r) {
                const int row = quad * 4 + r;
                const int g = nt * 2 + (l16 >> 3);
                PsB[wave * 1024 + row * 64 + ((g ^ (row & 7)) << 3) + (l16 & 7)] =
                    __float2bfloat16(sv[nt][r]);
            }
        __builtin_amdgcn_s_waitcnt(0xc07f);   // lgkmcnt(0): own-wave Ps visible

        // ---- O += P V  (shared group swizzle for pf and vf) ----
        for (int ks = 0; ks < 2; ++ks) {
            const int gp = ((ks * 4 + quad) ^ (l16 & 7)) << 3;
            short8 pf = *(const short8*)&PsB[wave * 1024 + l16 * 64 + gp];
            for (int nt = 0; nt < 8; ++nt) {
                const int d = nt * 16 + l16;
                short8 vf = *(const short8*)&VtB[bi * 8192 + d * 64 + gp];
                accO[nt] = __builtin_amdgcn_mfma_f32_16x16x32_bf16(
                    pf, vf, accO[nt], 0, 0, 0);
            }
        }
        __builtin_amdgcn_s_waitcnt(0xc07f);   // pf reads done before next tile's rewrite
    }

    bf16* Ob = O + (size_t)b * SS * DD + h * HDD;
    float inv[4];
    for (int r = 0; r < 4; ++r) inv[r] = 1.f / l_r[r];
    for (int nt = 0; nt < 8; ++nt)
        for (int r = 0; r < 4; ++r)
            Ob[(size_t)(q0 + wave * 16 + quad * 4 + r) * DD + nt * 16 + l16] =
                __float2bfloat16(accO[nt][r] * inv[r]);
}

extern "C" void kernel_launch(void* const* d_in, const int* in_sizes, int n_in,
                              void* d_out, int out_size, void* d_ws, size_t ws_size,
                              hipStream_t stream) {
    (void)in_sizes; (void)n_in; (void)out_size; (void)ws_size;
    const float* x     = (const float*)d_in[0];
    const float* freqs = (const float*)d_in[1];
    // d_in[2] = mask: exactly causal 0/-1e9 -> applied analytically in flash_attn
    const float* Wq    = (const float*)d_in[3];
    const float* Wdown = (const float*)d_in[4];
    const float* Wkup  = (const float*)d_in[5];
    const float* Wvup  = (const float*)d_in[6];
    const float* Wo    = (const float*)d_in[7];
    float* out = (float*)d_out;

    char* ws = (char*)d_ws;
    size_t off = 0;
    auto take = [&](size_t bytes) -> void* {
        void* p = ws + off;
        off += (bytes + 255) & ~(size_t)255;
        return p;
    };
    bf16* xb    = (bf16*)take((size_t)MR * DD * 2);         // 16.8 MB (later: attn)
    bf16* WqdT  = (bf16*)take((size_t)QRS * DD * 2);        // 10.5 MB (later: WoT)
    bf16* WkvT  = (bf16*)take((size_t)2 * DD * LATD * 2);   //  4.2 MB
    bf16* QC    = (bf16*)take((size_t)MR * QRS * 2);        // 21.0 MB [Q 2048 | ckv 512]
    bf16* KVb   = (bf16*)take((size_t)MR * 2 * DD * 2);     // 33.6 MB [tok][K | V]
    bf16* VTg   = (bf16*)take((size_t)BB * NH * HDD * SS * 2); // 16.8 MB (~103 MB total)
    bf16* attn  = xb;      // xb dead after QC gemm
    bf16* WoT   = WqdT;    // WqdT dead after QC gemm

    cast_f32_bf16<<<(MR * DD / 4) / 256, 256, 0, stream>>>(
        (const float4*)x, (ushort4*)xb, MR * DD / 4);

    transpose_cast<<<dim3(DD / 32, DD / 32), 256, 0, stream>>>(Wq, WqdT, DD, DD);
    transpose_cast<<<dim3(LATD / 32, DD / 32), 256, 0, stream>>>(
        Wdown, WqdT + (size_t)DD * DD, DD, LATD);
    transpose_cast<<<dim3(DD / 32, LATD / 32), 256, 0, stream>>>(Wkup, WkvT, LATD, DD);
    transpose_cast<<<dim3(DD / 32, LATD / 32), 256, 0, stream>>>(
        Wvup, WkvT + (size_t)DD * LATD, LATD, DD);

    // [Q | c_kv] = x [Wq | Wdown]   (M=4096, N=2560, K=2048)
    gemm_bt<false><<<dim3(QRS / 128, MR / 128), 256, 0, stream>>>(
        xb, WqdT, QC, MR, QRS, DD, DD, DD, QRS);
    // [K | V] = c_kv [Wkup | Wvup]  (M=4096, N=4096, K=512)
    gemm_bt<false><<<dim3(2 * DD / 128, MR / 128), 256, 0, stream>>>(
        QC + DD, WkvT, KVb, MR, 2 * DD, LATD, QRS, LATD, 2 * DD);

    transpose_v<<<dim3(SS / 64, HDD / 64, BB * NH), 256, 0, stream>>>(KVb, VTg);

    rope_qk<<<(MR * NH * 16) / 256, 256, 0, stream>>>(QC, KVb, freqs, MR * NH * 16);

    flash_attn<<<512, 512, 0, stream>>>(QC, KVb, VTg, attn);

    // out = attn Wo (fp32 epilogue straight to d_out)
    transpose_cast<<<dim3(DD / 32, DD / 32), 256, 0, stream>>>(Wo, WoT, DD, DD);
    gemm_bt<true><<<dim3(DD / 128, MR / 128), 256, 0, stream>>>(
        attn, WoT, out, MR, DD, DD, DD, DD, DD);
}

// Round 7
// 374.577 us; speedup vs baseline: 1.8109x; 1.1790x over previous
//
#include <hip/hip_runtime.h>
#include <hip/hip_bf16.h>
#include <math.h>

typedef __hip_bfloat16 bf16;
typedef __attribute__((ext_vector_type(8))) short short8;   // 8 x bf16 bits (4 VGPRs)
typedef __attribute__((ext_vector_type(4))) float f32x4;

static constexpr int BB   = 2;
static constexpr int SS   = 2048;
static constexpr int DD   = 2048;
static constexpr int NH   = 16;
static constexpr int HDD  = 128;
static constexpr int LATD = 512;
static constexpr int MR   = BB * SS;   // 4096 token rows
static constexpr int QRS  = DD + LATD; // 2560: row stride of merged [Q | c_kv] buffer

#if __has_builtin(__builtin_amdgcn_exp2f)
#define EXP2F(x) __builtin_amdgcn_exp2f(x)
#else
#define EXP2F(x) exp2f(x)
#endif

__device__ __forceinline__ void async_cp16(const void* g, void* l) {
    __builtin_amdgcn_global_load_lds(
        (const __attribute__((address_space(1))) void*)g,
        (__attribute__((address_space(3))) void*)l, 16, 0, 0);
}

__device__ __forceinline__ unsigned short bf_bits(bf16 v) {
    union { bf16 b; unsigned short u; } cv; cv.b = v; return cv.u;
}

// DPP lane-permute within 16-lane rows (VALU pipe — no LDS latency).
// dpp_ctrl must be an immediate -> template parameter.
template <int CTRL>
__device__ __forceinline__ float dpp_mov(float x) {
    int r = __builtin_amdgcn_update_dpp(0, __float_as_int(x), CTRL, 0xF, 0xF, true);
    return __int_as_float(r);
}
// 16-lane butterfly: quad_perm swap1 (0xB1), swap2 (0x4E), row_half_mirror (0x141),
// row_mirror (0x140).
__device__ __forceinline__ float dpp_max16(float x) {
    x = fmaxf(x, dpp_mov<0xB1>(x));
    x = fmaxf(x, dpp_mov<0x4E>(x));
    x = fmaxf(x, dpp_mov<0x141>(x));
    x = fmaxf(x, dpp_mov<0x140>(x));
    return x;
}
__device__ __forceinline__ float dpp_sum16(float x) {
    x += dpp_mov<0xB1>(x);
    x += dpp_mov<0x4E>(x);
    x += dpp_mov<0x141>(x);
    x += dpp_mov<0x140>(x);
    return x;
}

// ---------------- cast f32 -> bf16, vectorized x4 ----------------
__global__ void cast_f32_bf16(const float4* __restrict__ in,
                              ushort4* __restrict__ out, int n4) {
    int i = blockIdx.x * blockDim.x + threadIdx.x;
    if (i >= n4) return;
    float4 v = in[i];
    ushort4 o;
    o.x = bf_bits(__float2bfloat16(v.x));
    o.y = bf_bits(__float2bfloat16(v.y));
    o.z = bf_bits(__float2bfloat16(v.z));
    o.w = bf_bits(__float2bfloat16(v.w));
    out[i] = o;
}

// ---------- transpose + cast: in[rows][cols] f32 -> out[cols][rows] bf16 ----------
__global__ void transpose_cast(const float* __restrict__ in,
                               bf16* __restrict__ out, int rows, int cols) {
    __shared__ float tile[32][33];
    int tx = threadIdx.x & 31, ty = threadIdx.x >> 5;   // 32 x 8 threads
    int c0 = blockIdx.x * 32, r0 = blockIdx.y * 32;
    for (int i = 0; i < 32; i += 8)
        tile[ty + i][tx] = in[(size_t)(r0 + ty + i) * cols + c0 + tx];
    __syncthreads();
    for (int i = 0; i < 32; i += 8)
        out[(size_t)(c0 + ty + i) * rows + r0 + tx] =
            __float2bfloat16(tile[tx][ty + i]);
}

// ---- V pre-transpose: VT[bh][d][s] (bf16) from KV's V half, kv-group XOR swizzle ----
__global__ void transpose_v(const bf16* __restrict__ KV, bf16* __restrict__ VT) {
    __shared__ bf16 t[64][74];
    const int tid = threadIdx.x;
    const int s0 = blockIdx.x * 64, d0 = blockIdx.y * 64;
    const int bh = blockIdx.z, b = bh >> 4, h = bh & 15;
    const bf16* src = KV + (size_t)b * SS * 4096 + 2048 + h * 128 + d0;
    for (int p = 0; p < 2; ++p) {
        const int s = p * 32 + (tid >> 3), dc = (tid & 7) * 8;
        short8 v = *(const short8*)(src + (size_t)(s0 + s) * 4096 + dc);
        const bf16* ve = (const bf16*)&v;
        for (int e = 0; e < 8; ++e) t[s][dc + e] = ve[e];
    }
    __syncthreads();
    bf16* dst = VT + ((size_t)bh * HDD + d0) * SS + s0;
    for (int p = 0; p < 2; ++p) {
        const int d = p * 32 + (tid >> 3), g = tid & 7;
        short8 v; bf16* ve = (bf16*)&v;
        for (int e = 0; e < 8; ++e) ve[e] = t[g * 8 + e][d];
        const int gp = g ^ (d & 7);
        *(short8*)(dst + (size_t)d * SS + gp * 8) = v;
    }
}

// ------- double-buffered GEMM: C[M][N] = A[M][K(lda)] * Bt[N][K(ldb)]^T -------
template <bool OUT_F32>
__global__ __launch_bounds__(256) void gemm_bt(
    const bf16* __restrict__ A, const bf16* __restrict__ Bt,
    void* __restrict__ Cout, int M, int N, int K, int lda, int ldb, int ldc) {
    __shared__ bf16 As[2][128 * 32];
    __shared__ bf16 Bs[2][128 * 32];
    const int tid  = threadIdx.x;
    const int lane = tid & 63, wave = tid >> 6;
    const int quad = lane >> 4, l16 = lane & 15;
    const int row0 = blockIdx.y * 128, col0 = blockIdx.x * 128;
    const int wm = (wave >> 1) * 64, wn = (wave & 1) * 64;
    const int srow = lane >> 2;
    const int scol = (lane & 3) * 8;

    f32x4 acc[4][4];
    for (int i = 0; i < 4; ++i)
        for (int j = 0; j < 4; ++j)
            for (int r = 0; r < 4; ++r) acc[i][j][r] = 0.f;

    auto stage = [&](int k0, int bufi) {
        for (int c = 0; c < 2; ++c) {
            const int chunk = wave * 2 + c;
            const int r = chunk * 16 + srow;
            async_cp16(A  + (size_t)(row0 + r) * lda + k0 + scol, &As[bufi][chunk * 512]);
            async_cp16(Bt + (size_t)(col0 + r) * ldb + k0 + scol, &Bs[bufi][chunk * 512]);
        }
    };

    const int nk = K / 32;
    stage(0, 0);
    for (int ki = 0; ki < nk; ++ki) {
        __syncthreads();                    // drains stage ki; frees buf (ki+1)&1
        if (ki + 1 < nk) stage((ki + 1) * 32, (ki + 1) & 1);
        const int bi = ki & 1;
        short8 af[4], bfr[4];
        for (int t = 0; t < 4; ++t) {
            af[t]  = *(const short8*)&As[bi][(wm + t * 16 + l16) * 32 + quad * 8];
            bfr[t] = *(const short8*)&Bs[bi][(wn + t * 16 + l16) * 32 + quad * 8];
        }
        for (int i = 0; i < 4; ++i)
            for (int j = 0; j < 4; ++j)
                acc[i][j] = __builtin_amdgcn_mfma_f32_16x16x32_bf16(
                    af[i], bfr[j], acc[i][j], 0, 0, 0);
    }

    const int rbase = row0 + wm + quad * 4;
    const int cbase = col0 + wn + l16;
    if (OUT_F32) {
        float* C = (float*)Cout;
        for (int i = 0; i < 4; ++i)
            for (int j = 0; j < 4; ++j)
                for (int r = 0; r < 4; ++r)
                    C[(size_t)(rbase + i * 16 + r) * ldc + cbase + j * 16] = acc[i][j][r];
    } else {
        bf16* C = (bf16*)Cout;
        for (int i = 0; i < 4; ++i)
            for (int j = 0; j < 4; ++j)
                for (int r = 0; r < 4; ++r)
                    C[(size_t)(rbase + i * 16 + r) * ldc + cbase + j * 16] =
                        __float2bfloat16(acc[i][j][r]);
    }
}

// ------- RoPE on Q (stride 2560, pre-scaled by 1/sqrt(HD)*log2e) and K (stride 4096) -------
__global__ void rope_qk(bf16* __restrict__ Q, bf16* __restrict__ KV,
                        const float* __restrict__ freqs, int n) {
    const float QS = 0.08838834764831845f * 1.4426950408889634f;  // scale * log2(e)
    int idx = blockIdx.x * blockDim.x + threadIdx.x;
    if (idx >= n) return;
    const int pg  = idx & 15;
    const int h   = (idx >> 4) & (NH - 1);
    const int tok = idx >> 8;
    const int s   = tok & (SS - 1);
    const float4 f = *(const float4*)&freqs[s * 64 + pg * 4];
    float cs[4], sn[4];
    cs[0] = __cosf(f.x); sn[0] = __sinf(f.x);
    cs[1] = __cosf(f.y); sn[1] = __sinf(f.y);
    cs[2] = __cosf(f.z); sn[2] = __sinf(f.z);
    cs[3] = __cosf(f.w); sn[3] = __sinf(f.w);

    bf16* qp = Q  + (size_t)tok * QRS  + h * HDD + pg * 8;
    bf16* kp = KV + (size_t)tok * 4096 + h * HDD + pg * 8;
    for (int pass = 0; pass < 2; ++pass) {
        bf16* p = pass ? kp : qp;
        const float g = pass ? 1.f : QS;
        short8 v = *(const short8*)p;
        const bf16* ve = (const bf16*)&v;
        short8 o;
        bf16* oe = (bf16*)&o;
        for (int i = 0; i < 4; ++i) {
            float t0 = __bfloat162float(ve[2 * i]);
            float t1 = __bfloat162float(ve[2 * i + 1]);
            oe[2 * i]     = __float2bfloat16((t0 * cs[i] - t1 * sn[i]) * g);
            oe[2 * i + 1] = __float2bfloat16((t0 * sn[i] + t1 * cs[i]) * g);
        }
        *(short8*)p = o;
    }
}

// ------------- causal flash attention, BQ=128, BKV=64, double-buffered -------------
// 1D grid 512; CU-pair-complementary mapping: blocks j and j+256 share a CU
// (round-robin over 8 XCDs x 32 CUs), so bh=(j>>3)&31 (same for the pair -> L2
// K/V reuse) and qt = (j&256) ? (j&7) : 15-(j&7) (pair workloads sum to 34 tiles).
// 512 threads = 8 waves; wave w owns q rows [q0+w*16, +16). LDS = 80 KB -> 2 blocks/CU.
__global__ __launch_bounds__(512, 4) void flash_attn(
    const bf16* __restrict__ QC, const bf16* __restrict__ KV,
    const bf16* __restrict__ VTg, bf16* __restrict__ O) {
    const int j = blockIdx.x;
    const int bh = (j >> 3) & 31, q3 = j & 7;
    const int qt = (j & 256) ? q3 : 15 - q3;
    const int h = bh & (NH - 1), b = bh >> 4;
    const int q0 = qt * 128;
    const int tid = threadIdx.x, lane = tid & 63, wave = tid >> 6;
    const int quad = lane >> 4, l16 = lane & 15;

    __shared__ char smem[81920];
    bf16* KsB = (bf16*)smem;              // [2][8192]
    bf16* VtB = (bf16*)(smem + 32768);    // [2][8192]
    bf16* PsB = (bf16*)(smem + 65536);    // [8][1024]

    const bf16* Kb  = KV  + (size_t)b * SS * 4096 + h * HDD;
    const bf16* VTb = VTg + (size_t)bh * HDD * SS;
    const int krs = 4096;

    // Q A-frags: 4 k-steps (Q pre-scaled by 1/sqrt(HD)*log2e in rope)
    short8 qf[4];
    {
        const bf16* qrow = QC + (size_t)(b * SS + q0 + wave * 16 + l16) * QRS + h * HDD;
        for (int kk = 0; kk < 4; ++kk)
            qf[kk] = *(const short8*)(qrow + kk * 32 + quad * 8);
    }

    auto stage = [&](int kt, int bufi) {
        const int k0 = kt * 64;
        const int kk = wave >> 1, half = wave & 1;
        for (int i = 0; i < 2; ++i) {
            const int rbase = half * 32 + i * 16;
            async_cp16(Kb + (size_t)(k0 + rbase + (lane >> 2)) * krs
                           + kk * 32 + (lane & 3) * 8,
                       &KsB[bufi * 8192 + kk * 2048 + rbase * 32]);
        }
        for (int c2 = 0; c2 < 2; ++c2) {
            const int c = wave * 2 + c2;
            async_cp16(VTb + (size_t)(c * 8 + (lane >> 3)) * SS + k0 + (lane & 7) * 8,
                       &VtB[bufi * 8192 + c * 512]);
        }
    };

    f32x4 accO[8];
    for (int i = 0; i < 8; ++i)
        for (int r = 0; r < 4; ++r) accO[i][r] = 0.f;
    float m_r[4], l_r[4];
    for (int r = 0; r < 4; ++r) { m_r[r] = -1e30f; l_r[r] = 0.f; }

    const int ktMax = 2 * qt + 1;
    const int qwTop = q0 + wave * 16 + 15;   // this wave's last q row

    stage(0, 0);
    for (int kt = 0; kt <= ktMax; ++kt) {
        const int k0 = kt * 64;
        __syncthreads();                    // drains stage kt; frees buf (kt+1)&1
        if (kt < ktMax) stage(kt + 1, (kt + 1) & 1);
        const int bi = kt & 1;

        // wave-uniform skip: tile entirely above the causal diagonal for this wave
        if (k0 > qwTop) continue;

        // ---- S = Q K^T : [16 q][64 k] ----
        f32x4 sfr[4];
        for (int nt = 0; nt < 4; ++nt)
            for (int r = 0; r < 4; ++r) sfr[nt][r] = 0.f;
        for (int kk = 0; kk < 4; ++kk)
            for (int nt = 0; nt < 4; ++nt) {
                short8 kf = *(const short8*)
                    &KsB[bi * 8192 + kk * 2048 + (nt * 16 + l16) * 32 + quad * 8];
                sfr[nt] = __builtin_amdgcn_mfma_f32_16x16x32_bf16(
                    qf[kk], kf, sfr[nt], 0, 0, 0);
            }

        // ---- causal mask (block-uniform branch; S pre-scaled, log2 domain) ----
        float sv[4][4];
        for (int nt = 0; nt < 4; ++nt)
            for (int r = 0; r < 4; ++r) sv[nt][r] = sfr[nt][r];
        if (kt >= 2 * qt) {
            const int qg = q0 + wave * 16 + quad * 4;
            for (int nt = 0; nt < 4; ++nt) {
                const int kgl = k0 + nt * 16 + l16;
                for (int r = 0; r < 4; ++r)
                    if (kgl > qg + r) sv[nt][r] = -1e30f;
            }
        }
        // ---- online softmax in exp2 domain; DPP 16-lane reductions (VALU pipe) ----
        float rmax[4], alpha[4], psum[4];
        for (int r = 0; r < 4; ++r) {
            float m = fmaxf(fmaxf(sv[0][r], sv[1][r]), fmaxf(sv[2][r], sv[3][r]));
            rmax[r] = dpp_max16(m);
        }
        for (int r = 0; r < 4; ++r) {
            const float mnew = fmaxf(m_r[r], rmax[r]);
            alpha[r] = EXP2F(m_r[r] - mnew);
            m_r[r] = mnew;
        }
        for (int r = 0; r < 4; ++r) psum[r] = 0.f;
        for (int nt = 0; nt < 4; ++nt)
            for (int r = 0; r < 4; ++r) {
                const float p = EXP2F(sv[nt][r] - m_r[r]);
                sv[nt][r] = p;                 // sv becomes P
                psum[r] += p;
            }
        for (int r = 0; r < 4; ++r) {
            psum[r] = dpp_sum16(psum[r]);
            l_r[r] = l_r[r] * alpha[r] + psum[r];
        }
        for (int nt = 0; nt < 8; ++nt)
            for (int r = 0; r < 4; ++r) accO[nt][r] *= alpha[r];

        // ---- P -> LDS (C-layout write, group-XOR swizzle), re-read in A-layout ----
        for (int nt = 0; nt < 4; ++nt)
            for (int r = 0; r < 4; ++r) {
                const int row = quad * 4 + r;
                const int g = nt * 2 + (l16 >> 3);
                PsB[wave * 1024 + row * 64 + ((g ^ (row & 7)) << 3) + (l16 & 7)] =
                    __float2bfloat16(sv[nt][r]);
            }
        __builtin_amdgcn_s_waitcnt(0xc07f);   // lgkmcnt(0): own-wave Ps visible

        // ---- O += P V  (shared group swizzle for pf and vf) ----
        for (int ks = 0; ks < 2; ++ks) {
            const int gp = ((ks * 4 + quad) ^ (l16 & 7)) << 3;
            short8 pf = *(const short8*)&PsB[wave * 1024 + l16 * 64 + gp];
            for (int nt = 0; nt < 8; ++nt) {
                const int d = nt * 16 + l16;
                short8 vf = *(const short8*)&VtB[bi * 8192 + d * 64 + gp];
                accO[nt] = __builtin_amdgcn_mfma_f32_16x16x32_bf16(
                    pf, vf, accO[nt], 0, 0, 0);
            }
        }
        __builtin_amdgcn_s_waitcnt(0xc07f);   // pf reads done before next tile's rewrite
    }

    bf16* Ob = O + (size_t)b * SS * DD + h * HDD;
    float inv[4];
    for (int r = 0; r < 4; ++r) inv[r] = 1.f / l_r[r];
    for (int nt = 0; nt < 8; ++nt)
        for (int r = 0; r < 4; ++r)
            Ob[(size_t)(q0 + wave * 16 + quad * 4 + r) * DD + nt * 16 + l16] =
                __float2bfloat16(accO[nt][r] * inv[r]);
}

extern "C" void kernel_launch(void* const* d_in, const int* in_sizes, int n_in,
                              void* d_out, int out_size, void* d_ws, size_t ws_size,
                              hipStream_t stream) {
    (void)in_sizes; (void)n_in; (void)out_size; (void)ws_size;
    const float* x     = (const float*)d_in[0];
    const float* freqs = (const float*)d_in[1];
    // d_in[2] = mask: exactly causal 0/-1e9 -> applied analytically in flash_attn
    const float* Wq    = (const float*)d_in[3];
    const float* Wdown = (const float*)d_in[4];
    const float* Wkup  = (const float*)d_in[5];
    const float* Wvup  = (const float*)d_in[6];
    const float* Wo    = (const float*)d_in[7];
    float* out = (float*)d_out;

    char* ws = (char*)d_ws;
    size_t off = 0;
    auto take = [&](size_t bytes) -> void* {
        void* p = ws + off;
        off += (bytes + 255) & ~(size_t)255;
        return p;
    };
    bf16* xb    = (bf16*)take((size_t)MR * DD * 2);         // 16.8 MB (later: attn)
    bf16* WqdT  = (bf16*)take((size_t)QRS * DD * 2);        // 10.5 MB (later: WoT)
    bf16* WkvT  = (bf16*)take((size_t)2 * DD * LATD * 2);   //  4.2 MB
    bf16* QC    = (bf16*)take((size_t)MR * QRS * 2);        // 21.0 MB [Q 2048 | ckv 512]
    bf16* KVb   = (bf16*)take((size_t)MR * 2 * DD * 2);     // 33.6 MB [tok][K | V]
    bf16* VTg   = (bf16*)take((size_t)BB * NH * HDD * SS * 2); // 16.8 MB (~103 MB total)
    bf16* attn  = xb;      // xb dead after QC gemm
    bf16* WoT   = WqdT;    // WqdT dead after QC gemm

    cast_f32_bf16<<<(MR * DD / 4) / 256, 256, 0, stream>>>(
        (const float4*)x, (ushort4*)xb, MR * DD / 4);

    transpose_cast<<<dim3(DD / 32, DD / 32), 256, 0, stream>>>(Wq, WqdT, DD, DD);
    transpose_cast<<<dim3(LATD / 32, DD / 32), 256, 0, stream>>>(
        Wdown, WqdT + (size_t)DD * DD, DD, LATD);
    transpose_cast<<<dim3(DD / 32, LATD / 32), 256, 0, stream>>>(Wkup, WkvT, LATD, DD);
    transpose_cast<<<dim3(DD / 32, LATD / 32), 256, 0, stream>>>(
        Wvup, WkvT + (size_t)DD * LATD, LATD, DD);

    // [Q | c_kv] = x [Wq | Wdown]   (M=4096, N=2560, K=2048)
    gemm_bt<false><<<dim3(QRS / 128, MR / 128), 256, 0, stream>>>(
        xb, WqdT, QC, MR, QRS, DD, DD, DD, QRS);
    // [K | V] = c_kv [Wkup | Wvup]  (M=4096, N=4096, K=512)
    gemm_bt<false><<<dim3(2 * DD / 128, MR / 128), 256, 0, stream>>>(
        QC + DD, WkvT, KVb, MR, 2 * DD, LATD, QRS, LATD, 2 * DD);

    transpose_v<<<dim3(SS / 64, HDD / 64, BB * NH), 256, 0, stream>>>(KVb, VTg);

    rope_qk<<<(MR * NH * 16) / 256, 256, 0, stream>>>(QC, KVb, freqs, MR * NH * 16);

    flash_attn<<<512, 512, 0, stream>>>(QC, KVb, VTg, attn);

    // out = attn Wo (fp32 epilogue straight to d_out)
    transpose_cast<<<dim3(DD / 32, DD / 32), 256, 0, stream>>>(Wo, WoT, DD, DD);
    gemm_bt<true><<<dim3(DD / 128, MR / 128), 256, 0, stream>>>(
        attn, WoT, out, MR, DD, DD, DD, DD, DD);
}